// Round 12
// baseline (385.800 us; speedup 1.0000x reference)
//
#include <hip/hip_runtime.h>

#define B_   2
#define S_   2048
#define H_   2048
#define NH_  16
#define HS_  128
#define NORM_ 0.08838834764831845f          // 128^-0.5
#define L2B16 0.8304820237218407f           // log2(10000)/16

typedef unsigned short bf16_t;
typedef __bf16 bf16x8 __attribute__((ext_vector_type(8)));
typedef float  f32x4  __attribute__((ext_vector_type(4)));

__device__ __forceinline__ float b2f(bf16_t u) {
    return __uint_as_float(((unsigned int)u) << 16);
}
__device__ __forceinline__ bf16_t f2b(float f) {
    unsigned int x = __float_as_uint(f);
    x += 0x7fffu + ((x >> 16) & 1u);        // round-to-nearest-even
    return (bf16_t)(x >> 16);
}

__device__ __forceinline__ void async16(bf16_t* lds, const bf16_t* g) {
    __builtin_amdgcn_global_load_lds(
        (const __attribute__((address_space(1))) void*)g,
        (__attribute__((address_space(3))) void*)lds, 16, 0, 0);
}

__device__ __forceinline__ f32x4 mfma16(bf16x8 a, bf16x8 b, f32x4 c) {
    return __builtin_amdgcn_mfma_f32_16x16x32_bf16(a, b, c, 0, 0, 0);
}

#define BAR()        asm volatile("s_barrier" ::: "memory")
#define WAIT_VM0()   asm volatile("s_waitcnt vmcnt(0)" ::: "memory")

// ---------------- f32 -> bf16 convert (8 elems/thread) ----------------
__global__ __launch_bounds__(256) void cvt_bf16(const float* __restrict__ in,
                                                bf16_t* __restrict__ out) {
    const size_t i = (size_t)blockIdx.x * 256 + threadIdx.x;
    const float4* p = (const float4*)in + i * 2;
    float4 a = p[0], b = p[1];
    bf16_t o[8] = { f2b(a.x), f2b(a.y), f2b(a.z), f2b(a.w),
                    f2b(b.x), f2b(b.y), f2b(b.z), f2b(b.w) };
    *((bf16x8*)out + i) = *(const bf16x8*)o;
}

// ---------------- W (KxN f32) -> W^T (NxK bf16), 32x32 tiles ----------------
__global__ __launch_bounds__(256) void transpose_cvt(const float* __restrict__ W,
                                                     bf16_t* __restrict__ WT,
                                                     int K, int N) {
    __shared__ float tile[32][33];
    const int tx = threadIdx.x & 31, ty = threadIdx.x >> 5;
    const int n0 = blockIdx.x * 32, k0 = blockIdx.y * 32;
#pragma unroll
    for (int i = 0; i < 4; i++)
        tile[ty + i * 8][tx] = W[(size_t)(k0 + ty + i * 8) * N + n0 + tx];
    __syncthreads();
#pragma unroll
    for (int i = 0; i < 4; i++)
        WT[(size_t)(n0 + ty + i * 8) * K + k0 + tx] = f2b(tile[tx][ty + i * 8]);
}

// ---------------- 128x128 2-phase GEMM (proven; used for dense) ------------
template <int BF16OUT>
__global__ __launch_bounds__(256) void gemm_bias(const bf16_t* __restrict__ A,
                                                 const bf16_t* __restrict__ BT,
                                                 const float* __restrict__ bias,
                                                 void* __restrict__ Cv,
                                                 int M, int N, int K) {
    __shared__ __align__(16) bf16_t As[128 * 32];
    __shared__ __align__(16) bf16_t Bs[128 * 32];
    const int tid = threadIdx.x;
    const int wid = tid >> 6, lane = tid & 63;
    const int lr = lane & 15, ls = lane >> 4;
    const int wr = wid >> 1, wc = wid & 1;
    const size_t m0 = (size_t)blockIdx.y * 128, n0 = (size_t)blockIdx.x * 128;

    f32x4 acc[4][4];
#pragma unroll
    for (int m = 0; m < 4; m++)
#pragma unroll
        for (int n = 0; n < 4; n++) acc[m][n] = (f32x4){0.f, 0.f, 0.f, 0.f};

    const int srow = lane >> 2, sk = (lane & 3) * 8;

    for (int k0 = 0; k0 < K; k0 += 32) {
        __syncthreads();
#pragma unroll
        for (int j = 0; j < 2; j++) {
            const int rr = (wid * 2 + j) * 16 + srow;
            async16(As + (wid * 2 + j) * 512, A + (m0 + rr) * K + k0 + sk);
            async16(Bs + (wid * 2 + j) * 512, BT + (n0 + rr) * K + k0 + sk);
        }
        __syncthreads();
        bf16x8 af[4], bfr[4];
#pragma unroll
        for (int m = 0; m < 4; m++)
            af[m] = *(const bf16x8*)&As[(wr * 64 + m * 16 + lr) * 32 + ls * 8];
#pragma unroll
        for (int n = 0; n < 4; n++)
            bfr[n] = *(const bf16x8*)&Bs[(wc * 64 + n * 16 + lr) * 32 + ls * 8];
#pragma unroll
        for (int m = 0; m < 4; m++)
#pragma unroll
            for (int n = 0; n < 4; n++)
                acc[m][n] = mfma16(af[m], bfr[n], acc[m][n]);
    }

    float bv[4];
#pragma unroll
    for (int n = 0; n < 4; n++) bv[n] = bias[n0 + wc * 64 + n * 16 + lr];
#pragma unroll
    for (int m = 0; m < 4; m++)
#pragma unroll
        for (int n = 0; n < 4; n++)
#pragma unroll
            for (int j = 0; j < 4; j++) {
                const size_t row = m0 + wr * 64 + m * 16 + ls * 4 + j;
                const size_t col = n0 + wc * 64 + n * 16 + lr;
                const float v = acc[m][n][j] + bv[n];
                if (BF16OUT) ((bf16_t*)Cv)[row * N + col] = f2b(v);
                else         ((float*)Cv)[row * N + col] = v;
            }
}

// ---------------- shared staging helper (512-thread blocks) ----------------
__device__ __forceinline__ void st512(bf16_t* lds, const bf16_t* g,
                                      int K, int part, int tid) {
    const int idx = part * 512 + tid;
    const int row = idx >> 3, slot = idx & 7;
    async16(lds + idx * 8, g + (size_t)row * K + ((slot ^ (row & 7)) << 3));
}

#define LDAQ(dst, ab, q) do {                                                  \
    _Pragma("unroll")                                                          \
    for (int m = 0; m < 2; m++)                                                \
        _Pragma("unroll")                                                      \
        for (int ks = 0; ks < 2; ks++) {                                       \
            const int r = wm * 128 + (q) * 32 + m * 16 + lr;                   \
            dst[m][ks] = *(const bf16x8*)                                      \
                &(ab)[r * 64 + (((ks * 4 + ls) ^ (r & 7)) << 3)];              \
        }                                                                      \
} while (0)

// ---------------- 256x192 single-barrier GEMM (QKV) ------------------------
#define LDB3(bb) do {                                                          \
    _Pragma("unroll")                                                          \
    for (int n = 0; n < 3; n++)                                                \
        _Pragma("unroll")                                                      \
        for (int ks = 0; ks < 2; ks++) {                                       \
            const int r = wn * 48 + n * 16 + lr;                               \
            bfr[n][ks] = *(const bf16x8*)                                      \
                &(bb)[r * 64 + (((ks * 4 + ls) ^ (r & 7)) << 3)];              \
        }                                                                      \
} while (0)

#define MMA3(q, src) do {                                                      \
    __builtin_amdgcn_s_setprio(1);                                             \
    _Pragma("unroll")                                                          \
    for (int ks = 0; ks < 2; ks++)                                             \
        _Pragma("unroll")                                                      \
        for (int n = 0; n < 3; n++)                                            \
            _Pragma("unroll")                                                  \
            for (int m = 0; m < 2; m++)                                        \
                acc[(q) * 2 + m][n] =                                          \
                    mfma16(src[m][ks], bfr[n][ks], acc[(q) * 2 + m][n]);       \
    __builtin_amdgcn_s_setprio(0);                                             \
} while (0)

__global__ __launch_bounds__(512, 2) void gemm_qkv(const bf16_t* __restrict__ A,
                                                   const bf16_t* __restrict__ BT,
                                                   const float* __restrict__ bias,
                                                   bf16_t* __restrict__ C,
                                                   int M, int N, int K) {
    __shared__ __align__(16) bf16_t As[2][256 * 64];
    __shared__ __align__(16) bf16_t Bs[2][192 * 64];

    const int nwg = (int)(gridDim.x * gridDim.y);
    const int id  = (int)(blockIdx.y * gridDim.x + blockIdx.x);
    const int wg  = (id & 7) * (nwg >> 3) + (id >> 3);      // XCD-bijective
    const int bx  = wg % (int)gridDim.x, by = wg / (int)gridDim.x;

    const int tid = threadIdx.x;
    const int wid = tid >> 6, lane = tid & 63;
    const int lr = lane & 15, ls = lane >> 4;
    const int wm = wid >> 2, wn = wid & 3;
    const size_t m0 = (size_t)by * 256, n0 = (size_t)bx * 192;

    const bf16_t* Ab = A + m0 * K;
    const bf16_t* Bb = BT + n0 * K;

    f32x4 acc[8][3];
#pragma unroll
    for (int m = 0; m < 8; m++)
#pragma unroll
        for (int n = 0; n < 3; n++) acc[m][n] = (f32x4){0.f, 0.f, 0.f, 0.f};
    bf16x8 bfr[3][2];
    bf16x8 afP[2][2], afQ[2][2];

#pragma unroll
    for (int p = 0; p < 4; p++) st512(As[0], Ab, K, p, tid);
#pragma unroll
    for (int p = 0; p < 3; p++) st512(Bs[0], Bb, K, p, tid);
    WAIT_VM0();
    BAR();

    const int nt = K >> 6;
#pragma unroll 1
    for (int i = 0; i < nt; ++i) {
        const int c = i & 1;
        const bf16_t* Ac = As[c];
        const bf16_t* Bc = Bs[c];
        if (i + 1 < nt) {
            const size_t ko = (size_t)(i + 1) * 64;
            bf16_t* Ad = As[c ^ 1];
            bf16_t* Bd = Bs[c ^ 1];
#pragma unroll
            for (int p = 0; p < 4; p++) st512(Ad, Ab + ko, K, p, tid);
#pragma unroll
            for (int p = 0; p < 3; p++) st512(Bd, Bb + ko, K, p, tid);
        }
        __builtin_amdgcn_sched_barrier(0);
        LDAQ(afP, Ac, 0);
        LDB3(Bc);
        LDAQ(afQ, Ac, 1);
        MMA3(0, afP);
        LDAQ(afP, Ac, 2);
        MMA3(1, afQ);
        LDAQ(afQ, Ac, 3);
        MMA3(2, afP);
        MMA3(3, afQ);
        WAIT_VM0();
        BAR();
    }

    float bv[3];
#pragma unroll
    for (int n = 0; n < 3; n++) bv[n] = bias[n0 + wn * 48 + n * 16 + lr];
#pragma unroll
    for (int mm = 0; mm < 8; mm++)
#pragma unroll
        for (int n = 0; n < 3; n++)
#pragma unroll
            for (int j = 0; j < 4; j++) {
                const size_t row = m0 + wm * 128 + mm * 16 + ls * 4 + j;
                const size_t col = n0 + wn * 48 + n * 16 + lr;
                C[row * N + col] = f2b(acc[mm][n][j] + bv[n]);
            }
}

// ---------------- RoPE on Q,K; K written in fragment-major layout -----------
// Kf[bh][t=s>>4][dk=d0>>5][lane=((d0&31)>>3)*16 + (s&15)][8]
__global__ __launch_bounds__(256) void rope_qk(const bf16_t* __restrict__ qkv,
                                               const int* __restrict__ pos_ids,
                                               bf16_t* __restrict__ Qo,
                                               bf16_t* __restrict__ Kf) {
    const size_t gid = (size_t)blockIdx.x * 256 + threadIdx.x;
    const int d8 = (int)(gid & 15);
    const size_t t1 = gid >> 4;
    const int which = (int)(t1 & 1);
    const size_t t2 = t1 >> 1;
    const int nh = (int)(t2 & 15);
    const size_t bs = t2 >> 4;                  // b*S + s
    const int s = (int)(bs & (S_ - 1));
    const int b = (int)(bs >> 11);

    const bf16_t* src = qkv + bs * (3 * H_) + nh * 384 + which * 128 + d8 * 8;
    bf16x8 xv = *(const bf16x8*)src;
    const bf16_t* xu = (const bf16_t*)&xv;

    float xf[8];
#pragma unroll
    for (int i = 0; i < 8; i++) xf[i] = b2f(xu[i]);
    const int d0 = d8 * 8;
    if (d0 < 32) {
        const float pos = (float)pos_ids[bs];
        bf16x8 yv = *(const bf16x8*)(src + ((d0 < 16) ? 16 : -16));
        const bf16_t* yu = (const bf16_t*)&yv;
#pragma unroll
        for (int i = 0; i < 8; i++) {
            const int d = d0 + i;
            const float th = pos * exp2f(-(float)(d & 15) * L2B16);
            const float c = cosf(th), sn = sinf(th);
            const float rot = (d < 16) ? -b2f(yu[i]) : b2f(yu[i]);
            xf[i] = xf[i] * c + rot * sn;
        }
    }
    bf16_t ou[8];
#pragma unroll
    for (int i = 0; i < 8; i++) ou[i] = f2b(xf[i]);

    const int bh = b * NH_ + nh;
    if (which == 0) {
        bf16_t* dst = Qo + ((size_t)bh * S_ + s) * HS_ + d0;
        *(bf16x8*)dst = *(const bf16x8*)ou;
    } else {
        const int lane = (((d0 & 31) >> 3) << 4) + (s & 15);
        const size_t idx = ((((size_t)bh * 128 + (s >> 4)) * 4 + (d0 >> 5)) * 64 + lane) * 8;
        *(bf16x8*)&Kf[idx] = *(const bf16x8*)ou;
    }
}

// ---------------- V -> fragment-major Vf --------------------------------
// Vf[bh][kb=s>>6][dt=d>>4][hh=((s&63)>>5)][lane=((s&31)>>3)*16 + (d&15)][8]
// (8 elems = s..s+7 at fixed d)
__global__ __launch_bounds__(256) void vfrag(const bf16_t* __restrict__ qkv,
                                             bf16_t* __restrict__ Vf) {
    __shared__ bf16_t t[128][130];
    const int bh = (int)blockIdx.x >> 4;
    const int s0 = ((int)blockIdx.x & 15) << 7;
    const int b = bh >> 4, h = bh & 15;
    const int tid = threadIdx.x;

    const int dc = tid & 15, sl = tid >> 4;
    const bf16_t* src = qkv + ((size_t)b * S_ + s0) * (3 * H_) + h * 384 + 256 + dc * 8;
#pragma unroll
    for (int c = 0; c < 8; c++) {
        const int s = sl + c * 16;
        bf16x8 v = *(const bf16x8*)(src + (size_t)s * (3 * H_));
        *(bf16x8*)&t[s][dc * 8] = v;
    }
    __syncthreads();
    const int sc = tid & 15, dl = tid >> 4;     // sc: 8-s group, dl: d low
#pragma unroll
    for (int c = 0; c < 8; c++) {
        const int d = dl + c * 16;
        bf16_t o[8];
#pragma unroll
        for (int i = 0; i < 8; i++) o[i] = t[sc * 8 + i][d];
        const int kb = (s0 >> 6) + (sc >> 3);
        const int hh = (sc >> 2) & 1;
        const int ls = sc & 3;
        const size_t idx = (((((size_t)bh * 32 + kb) * 8 + (d >> 4)) * 2 + hh) * 64
                            + ls * 16 + (d & 15)) * 8;
        *(bf16x8*)&Vf[idx] = *(const bf16x8*)o;
    }
}

// ---------------- causal flash attention v6: barrier-free, global-direct ----
// K/V read straight from L2-resident fragment-major layouts (1KB coalesced
// loads). No K/V LDS, no staging, no vmcnt asm, no per-step barriers.
// Block = (bh, pair p): q-tiles (15-p) then p, 128 rows (4 waves x 32 rows,
// u=0,1 subtiles sharing kf/vf). 36 uniform steps/block; bh&7 = XCD.
__global__ __launch_bounds__(256) void attn_fwd(const bf16_t* __restrict__ Q,
                                                const bf16_t* __restrict__ Kf,
                                                const bf16_t* __restrict__ Vf,
                                                const float* __restrict__ amask,
                                                bf16_t* __restrict__ ctx) {
    __shared__ __align__(16) bf16_t Ps[4][16 * 72];
    __shared__ __align__(16) float  ams[S_];

    const int bh = (int)blockIdx.x;               // XCD = bh & 7
    const int pr = (int)blockIdx.y;               // 0..7
    const int b = bh >> 4, h = bh & 15;
    const int tid = threadIdx.x, wid = tid >> 6, lane = tid & 63;
    const int lr = lane & 15, ls = lane >> 4;
    const bf16_t* Kb = Kf + (size_t)bh * S_ * HS_;   // 128*4*64*8 = S*HS
    const bf16_t* Vb = Vf + (size_t)bh * S_ * HS_;   // 32*8*2*64*8 = S*HS

    {   // mask row -> LDS (8 floats/thread, coalesced)
        const float* amr = amask + (size_t)b * S_;
        float4 v0 = *(const float4*)&amr[tid * 8];
        float4 v1 = *(const float4*)&amr[tid * 8 + 4];
        *(float4*)&ams[tid * 8]     = v0;
        *(float4*)&ams[tid * 8 + 4] = v1;
    }
    __syncthreads();                               // only block-wide sync

#pragma unroll 1
    for (int half = 0; half < 2; ++half) {
        const int qt = half ? pr : (15 - pr);
        const int q0 = qt << 7;                   // 128-row q tile
        const int qb = q0 + wid * 32;             // wave's 32-row q base

        bf16x8 qf[2][4];
#pragma unroll
        for (int u = 0; u < 2; u++) {
            const bf16_t* qp = Q + ((size_t)bh * S_ + qb + u * 16 + lr) * HS_;
#pragma unroll
            for (int dk = 0; dk < 4; dk++)
                qf[u][dk] = *(const bf16x8*)(qp + dk * 32 + ls * 8);
        }

        float mrun[2] = { -3.0e38f, -3.0e38f }, lrun[2] = { 0.f, 0.f };
        f32x4 oacc[2][8];
#pragma unroll
        for (int u = 0; u < 2; u++)
#pragma unroll
            for (int dt = 0; dt < 8; dt++) oacc[u][dt] = (f32x4){0.f, 0.f, 0.f, 0.f};

        const int nsteps = 2 * qt + 2;
#pragma unroll 1
        for (int step = 0; step < nsteps; ++step) {
            const int kv0 = step << 6;

            // QK^T: kf fragments straight from global (L2/L1), shared across u
            f32x4 sacc[2][4];
#pragma unroll
            for (int u = 0; u < 2; u++)
#pragma unroll
                for (int tt = 0; tt < 4; tt++) sacc[u][tt] = (f32x4){0.f, 0.f, 0.f, 0.f};
#pragma unroll
            for (int tt = 0; tt < 4; tt++) {
                bf16x8 kf[4];
#pragma unroll
                for (int dk = 0; dk < 4; dk++)
                    kf[dk] = *(const bf16x8*)
                        &Kb[((((size_t)step * 4 + tt) * 4 + dk) * 64 + lane) * 8];
#pragma unroll
                for (int dk = 0; dk < 4; dk++) {
                    sacc[0][tt] = mfma16(kf[dk], qf[0][dk], sacc[0][tt]);
                    sacc[1][tt] = mfma16(kf[dk], qf[1][dk], sacc[1][tt]);
                }
            }

            const bool diag = (step >= 2 * qt);
            bf16x8 pfr[2][2];
#pragma unroll
            for (int u = 0; u < 2; u++) {
                const int qrow = qb + u * 16 + lr;
                float sv[4][4];
                float rmax = -3.0e38f;
#pragma unroll
                for (int tt = 0; tt < 4; tt++) {
                    const float4 amv = *(const float4*)&ams[kv0 + tt * 16 + ls * 4];
                    const float amj[4] = { amv.x, amv.y, amv.z, amv.w };
#pragma unroll
                    for (int j = 0; j < 4; j++) {
                        const int kvp = kv0 + tt * 16 + ls * 4 + j;
                        float v = sacc[u][tt][j] * NORM_ + amj[j];
                        if (diag && kvp > qrow) v = -3.0e38f;
                        sv[tt][j] = v;
                        rmax = fmaxf(rmax, v);
                    }
                }
                rmax = fmaxf(rmax, __shfl_xor(rmax, 16));
                rmax = fmaxf(rmax, __shfl_xor(rmax, 32));

                if (!__all((int)(rmax <= mrun[u]))) {
                    const float mnew = fmaxf(mrun[u], rmax);
                    const float sc = __expf(mrun[u] - mnew);
                    lrun[u] *= sc;
                    mrun[u] = mnew;
                    float scb[4];
#pragma unroll
                    for (int j = 0; j < 4; j++) scb[j] = __shfl(sc, ls * 4 + j);
#pragma unroll
                    for (int dt = 0; dt < 8; dt++)
#pragma unroll
                        for (int j = 0; j < 4; j++) oacc[u][dt][j] *= scb[j];
                }

                float psum = 0.f;
#pragma unroll
                for (int tt = 0; tt < 4; tt++) {
                    const float p0 = __expf(sv[tt][0] - mrun[u]);
                    const float p1 = __expf(sv[tt][1] - mrun[u]);
                    const float p2 = __expf(sv[tt][2] - mrun[u]);
                    const float p3 = __expf(sv[tt][3] - mrun[u]);
                    psum += (p0 + p1) + (p2 + p3);
                    const unsigned pk0 = (unsigned)f2b(p0) | ((unsigned)f2b(p1) << 16);
                    const unsigned pk1 = (unsigned)f2b(p2) | ((unsigned)f2b(p3) << 16);
                    *(unsigned*)&Ps[wid][lr * 72 + tt * 16 + ls * 4]     = pk0;
                    *(unsigned*)&Ps[wid][lr * 72 + tt * 16 + ls * 4 + 2] = pk1;
                }
                psum += __shfl_xor(psum, 16);
                psum += __shfl_xor(psum, 32);
                lrun[u] += psum;

                pfr[u][0] = *(const bf16x8*)&Ps[wid][lr * 72 + ls * 8];
                pfr[u][1] = *(const bf16x8*)&Ps[wid][lr * 72 + 32 + ls * 8];
            }

            // PV: vf fragments straight from global, shared across u
#pragma unroll
            for (int dt = 0; dt < 8; dt++) {
                bf16x8 vf[2];
#pragma unroll
                for (int hh = 0; hh < 2; hh++)
                    vf[hh] = *(const bf16x8*)
                        &Vb[((((size_t)step * 8 + dt) * 2 + hh) * 64 + lane) * 8];
#pragma unroll
                for (int hh = 0; hh < 2; hh++) {
                    oacc[0][dt] = mfma16(pfr[0][hh], vf[hh], oacc[0][dt]);
                    oacc[1][dt] = mfma16(pfr[1][hh], vf[hh], oacc[1][dt]);
                }
            }
        }

#pragma unroll
        for (int u = 0; u < 2; u++) {
            const float inv = 1.0f / lrun[u];
            float invj[4];
#pragma unroll
            for (int j = 0; j < 4; j++) invj[j] = __shfl(inv, ls * 4 + j);
#pragma unroll
            for (int j = 0; j < 4; j++) {
                bf16_t* dst = ctx + ((size_t)b * S_ + qb + u * 16 + ls * 4 + j) * H_ + h * HS_;
#pragma unroll
                for (int dt = 0; dt < 8; dt++)
                    dst[dt * 16 + lr] = f2b(oacc[u][dt][j] * invj[j]);
            }
        }
    }
}

extern "C" void kernel_launch(void* const* d_in, const int* in_sizes, int n_in,
                              void* d_out, int out_size, void* d_ws, size_t ws_size,
                              hipStream_t stream) {
    const float* hs   = (const float*)d_in[0];
    const float* am   = (const float*)d_in[1];
    const int*   pos  = (const int*)d_in[2];
    const float* Wqkv = (const float*)d_in[3];
    const float* bqkv = (const float*)d_in[4];
    const float* Wd   = (const float*)d_in[5];
    const float* bd   = (const float*)d_in[6];
    float* out = (float*)d_out;
    char*  ws  = (char*)d_ws;

    const size_t MB = 1024 * 1024;
    bf16_t* X    = (bf16_t*)(ws);              // 16 MB (reused as ctx)
    bf16_t* WqT  = (bf16_t*)(ws + 16 * MB);    // 24 MB
    bf16_t* WdT  = (bf16_t*)(ws + 40 * MB);    // 8 MB
    bf16_t* QKVb = (bf16_t*)(ws + 48 * MB);    // 48 MB
    bf16_t* Qb   = (bf16_t*)(ws + 96 * MB);    // 16 MB
    bf16_t* Kfb  = (bf16_t*)(ws + 112 * MB);   // 16 MB (fragment-major K)
    bf16_t* Vfb  = (bf16_t*)(ws + 128 * MB);   // 16 MB (fragment-major V)
    bf16_t* ctx  = X;

    cvt_bf16<<<4096, 256, 0, stream>>>(hs, X);
    transpose_cvt<<<dim3(6144 / 32, 2048 / 32), 256, 0, stream>>>(Wqkv, WqT, 2048, 6144);
    transpose_cvt<<<dim3(2048 / 32, 2048 / 32), 256, 0, stream>>>(Wd, WdT, 2048, 2048);
    gemm_qkv<<<dim3(32, 16), 512, 0, stream>>>(X, WqT, bqkv, QKVb, 4096, 6144, 2048);
    rope_qk<<<8192, 256, 0, stream>>>(QKVb, pos, Qb, Kfb);
    vfrag<<<512, 256, 0, stream>>>(QKVb, Vfb);
    attn_fwd<<<dim3(32, 8), 256, 0, stream>>>(Qb, Kfb, Vfb, am, ctx);
    gemm_bias<0><<<dim3(2048 / 128, 4096 / 128), 256, 0, stream>>>(ctx, WdT, bd, out,
                                                                   4096, 2048, 2048);
}

// Round 13
// 310.317 us; speedup vs baseline: 1.2432x; 1.2432x over previous
//
#include <hip/hip_runtime.h>

#define B_   2
#define S_   2048
#define H_   2048
#define NH_  16
#define HS_  128
#define NORM_ 0.08838834764831845f          // 128^-0.5
#define L2B16 0.8304820237218407f           // log2(10000)/16

typedef unsigned short bf16_t;
typedef __bf16 bf16x8 __attribute__((ext_vector_type(8)));
typedef float  f32x4  __attribute__((ext_vector_type(4)));

__device__ __forceinline__ float b2f(bf16_t u) {
    return __uint_as_float(((unsigned int)u) << 16);
}
__device__ __forceinline__ bf16_t f2b(float f) {
    unsigned int x = __float_as_uint(f);
    x += 0x7fffu + ((x >> 16) & 1u);        // round-to-nearest-even
    return (bf16_t)(x >> 16);
}

__device__ __forceinline__ void async16(bf16_t* lds, const bf16_t* g) {
    __builtin_amdgcn_global_load_lds(
        (const __attribute__((address_space(1))) void*)g,
        (__attribute__((address_space(3))) void*)lds, 16, 0, 0);
}

__device__ __forceinline__ f32x4 mfma16(bf16x8 a, bf16x8 b, f32x4 c) {
    return __builtin_amdgcn_mfma_f32_16x16x32_bf16(a, b, c, 0, 0, 0);
}

#define BAR()        asm volatile("s_barrier" ::: "memory")
#define WAIT_VM0()   asm volatile("s_waitcnt vmcnt(0)" ::: "memory")
#define WAIT_VM8()   asm volatile("s_waitcnt vmcnt(8)" ::: "memory")

// ---------------- f32 -> bf16 convert (8 elems/thread) ----------------
__global__ __launch_bounds__(256) void cvt_bf16(const float* __restrict__ in,
                                                bf16_t* __restrict__ out) {
    const size_t i = (size_t)blockIdx.x * 256 + threadIdx.x;
    const float4* p = (const float4*)in + i * 2;
    float4 a = p[0], b = p[1];
    bf16_t o[8] = { f2b(a.x), f2b(a.y), f2b(a.z), f2b(a.w),
                    f2b(b.x), f2b(b.y), f2b(b.z), f2b(b.w) };
    *((bf16x8*)out + i) = *(const bf16x8*)o;
}

// ---------------- W (KxN f32) -> W^T (NxK bf16), 64x64 tiles, vectorized ----
__global__ __launch_bounds__(256) void transpose_cvt(const float* __restrict__ W,
                                                     bf16_t* __restrict__ WT,
                                                     int K, int N) {
    __shared__ float t[64][65];
    const int n0 = blockIdx.x * 64, k0 = blockIdx.y * 64;
    const int tid = threadIdx.x;
    const int cx = tid & 15, r0 = tid >> 4;
#pragma unroll
    for (int p = 0; p < 4; p++) {
        const int row = p * 16 + r0;
        const float4 v = *(const float4*)&W[(size_t)(k0 + row) * N + n0 + cx * 4];
        t[row][cx * 4 + 0] = v.x;
        t[row][cx * 4 + 1] = v.y;
        t[row][cx * 4 + 2] = v.z;
        t[row][cx * 4 + 3] = v.w;
    }
    __syncthreads();
    const int n = tid >> 2, k8 = tid & 3;
#pragma unroll
    for (int p = 0; p < 2; p++) {
        const int kk = (k8 + p * 4) * 8;
        bf16_t o[8];
#pragma unroll
        for (int i = 0; i < 8; i++) o[i] = f2b(t[kk + i][n]);
        *(bf16x8*)&WT[(size_t)(n0 + n) * K + k0 + kk] = *(const bf16x8*)o;
    }
}

// ---------------- 128x128 2-phase GEMM (dense), XCD 8x8-tiled --------------
// grid MUST be (16, 32). XCD k owns an 8bx x 8by tile: unique fetch/XCD
// = 4MB A + 4MB B (vs A-all + 2 bx-strips with the default raster).
template <int BF16OUT>
__global__ __launch_bounds__(256) void gemm_bias(const bf16_t* __restrict__ A,
                                                 const bf16_t* __restrict__ BT,
                                                 const float* __restrict__ bias,
                                                 void* __restrict__ Cv,
                                                 int M, int N, int K) {
    __shared__ __align__(16) bf16_t As[128 * 32];
    __shared__ __align__(16) bf16_t Bs[128 * 32];
    const int id  = (int)(blockIdx.y * gridDim.x + blockIdx.x);
    const int xcd = id & 7, j = id >> 3;
    const int bx  = (xcd & 1) * 8 + (j & 7);       // 0..15
    const int by  = (xcd >> 1) * 8 + (j >> 3);     // 0..31
    const int tid = threadIdx.x;
    const int wid = tid >> 6, lane = tid & 63;
    const int lr = lane & 15, ls = lane >> 4;
    const int wr = wid >> 1, wc = wid & 1;
    const size_t m0 = (size_t)by * 128, n0 = (size_t)bx * 128;

    f32x4 acc[4][4];
#pragma unroll
    for (int m = 0; m < 4; m++)
#pragma unroll
        for (int n = 0; n < 4; n++) acc[m][n] = (f32x4){0.f, 0.f, 0.f, 0.f};

    const int srow = lane >> 2, sk = (lane & 3) * 8;

    for (int k0 = 0; k0 < K; k0 += 32) {
        __syncthreads();
#pragma unroll
        for (int jj = 0; jj < 2; jj++) {
            const int rr = (wid * 2 + jj) * 16 + srow;
            async16(As + (wid * 2 + jj) * 512, A + (m0 + rr) * K + k0 + sk);
            async16(Bs + (wid * 2 + jj) * 512, BT + (n0 + rr) * K + k0 + sk);
        }
        __syncthreads();
        bf16x8 af[4], bfr[4];
#pragma unroll
        for (int m = 0; m < 4; m++)
            af[m] = *(const bf16x8*)&As[(wr * 64 + m * 16 + lr) * 32 + ls * 8];
#pragma unroll
        for (int n = 0; n < 4; n++)
            bfr[n] = *(const bf16x8*)&Bs[(wc * 64 + n * 16 + lr) * 32 + ls * 8];
#pragma unroll
        for (int m = 0; m < 4; m++)
#pragma unroll
            for (int n = 0; n < 4; n++)
                acc[m][n] = mfma16(af[m], bfr[n], acc[m][n]);
    }

    float bv[4];
#pragma unroll
    for (int n = 0; n < 4; n++) bv[n] = bias[n0 + wc * 64 + n * 16 + lr];
#pragma unroll
    for (int m = 0; m < 4; m++)
#pragma unroll
        for (int n = 0; n < 4; n++)
#pragma unroll
            for (int jj = 0; jj < 4; jj++) {
                const size_t row = m0 + wr * 64 + m * 16 + ls * 4 + jj;
                const size_t col = n0 + wc * 64 + n * 16 + lr;
                const float v = acc[m][n][jj] + bv[n];
                if (BF16OUT) ((bf16_t*)Cv)[row * N + col] = f2b(v);
                else         ((float*)Cv)[row * N + col] = v;
            }
}

// ---------------- shared staging helper (512-thread blocks) ----------------
__device__ __forceinline__ void st512(bf16_t* lds, const bf16_t* g,
                                      int K, int part, int tid) {
    const int idx = part * 512 + tid;
    const int row = idx >> 3, slot = idx & 7;
    async16(lds + idx * 8, g + (size_t)row * K + ((slot ^ (row & 7)) << 3));
}

#define LDAQ(dst, ab, q) do {                                                  \
    _Pragma("unroll")                                                          \
    for (int m = 0; m < 2; m++)                                                \
        _Pragma("unroll")                                                      \
        for (int ks = 0; ks < 2; ks++) {                                       \
            const int r = wm * 128 + (q) * 32 + m * 16 + lr;                   \
            dst[m][ks] = *(const bf16x8*)                                      \
                &(ab)[r * 64 + (((ks * 4 + ls) ^ (r & 7)) << 3)];              \
        }                                                                      \
} while (0)

// ---------------- 256x192 single-barrier GEMM (QKV), XCD 8x8-tiled ----------
// grid MUST be (32, 16). XCD k owns an 8bx x 8by tile: unique fetch/XCD
// = 8MB A + 6.3MB B = 14.3MB (vs 2MB A + ALL 25MB of B with the 1-D swizzle
// -> measured 205MB fetch). Per-K-step resident slice ~330KB << 4MB L2.
#define LDB3(bb) do {                                                          \
    _Pragma("unroll")                                                          \
    for (int n = 0; n < 3; n++)                                                \
        _Pragma("unroll")                                                      \
        for (int ks = 0; ks < 2; ks++) {                                       \
            const int r = wn * 48 + n * 16 + lr;                               \
            bfr[n][ks] = *(const bf16x8*)                                      \
                &(bb)[r * 64 + (((ks * 4 + ls) ^ (r & 7)) << 3)];              \
        }                                                                      \
} while (0)

#define MMA3(q, src) do {                                                      \
    __builtin_amdgcn_s_setprio(1);                                             \
    _Pragma("unroll")                                                          \
    for (int ks = 0; ks < 2; ks++)                                             \
        _Pragma("unroll")                                                      \
        for (int n = 0; n < 3; n++)                                            \
            _Pragma("unroll")                                                  \
            for (int m = 0; m < 2; m++)                                        \
                acc[(q) * 2 + m][n] =                                          \
                    mfma16(src[m][ks], bfr[n][ks], acc[(q) * 2 + m][n]);       \
    __builtin_amdgcn_s_setprio(0);                                             \
} while (0)

__global__ __launch_bounds__(512, 2) void gemm_qkv(const bf16_t* __restrict__ A,
                                                   const bf16_t* __restrict__ BT,
                                                   const float* __restrict__ bias,
                                                   bf16_t* __restrict__ C,
                                                   int M, int N, int K) {
    __shared__ __align__(16) bf16_t As[2][256 * 64];
    __shared__ __align__(16) bf16_t Bs[2][192 * 64];

    const int id  = (int)(blockIdx.y * gridDim.x + blockIdx.x);
    const int xcd = id & 7, j = id >> 3;
    const int bx  = (xcd & 3) * 8 + (j & 7);       // 0..31
    const int by  = (xcd >> 2) * 8 + (j >> 3);     // 0..15

    const int tid = threadIdx.x;
    const int wid = tid >> 6, lane = tid & 63;
    const int lr = lane & 15, ls = lane >> 4;
    const int wm = wid >> 2, wn = wid & 3;
    const size_t m0 = (size_t)by * 256, n0 = (size_t)bx * 192;

    const bf16_t* Ab = A + m0 * K;
    const bf16_t* Bb = BT + n0 * K;

    f32x4 acc[8][3];
#pragma unroll
    for (int m = 0; m < 8; m++)
#pragma unroll
        for (int n = 0; n < 3; n++) acc[m][n] = (f32x4){0.f, 0.f, 0.f, 0.f};
    bf16x8 bfr[3][2];
    bf16x8 afP[2][2], afQ[2][2];

#pragma unroll
    for (int p = 0; p < 4; p++) st512(As[0], Ab, K, p, tid);
#pragma unroll
    for (int p = 0; p < 3; p++) st512(Bs[0], Bb, K, p, tid);
    WAIT_VM0();
    BAR();

    const int nt = K >> 6;
#pragma unroll 1
    for (int i = 0; i < nt; ++i) {
        const int c = i & 1;
        const bf16_t* Ac = As[c];
        const bf16_t* Bc = Bs[c];
        if (i + 1 < nt) {
            const size_t ko = (size_t)(i + 1) * 64;
            bf16_t* Ad = As[c ^ 1];
            bf16_t* Bd = Bs[c ^ 1];
#pragma unroll
            for (int p = 0; p < 4; p++) st512(Ad, Ab + ko, K, p, tid);
#pragma unroll
            for (int p = 0; p < 3; p++) st512(Bd, Bb + ko, K, p, tid);
        }
        __builtin_amdgcn_sched_barrier(0);
        LDAQ(afP, Ac, 0);
        LDB3(Bc);
        LDAQ(afQ, Ac, 1);
        MMA3(0, afP);
        LDAQ(afP, Ac, 2);
        MMA3(1, afQ);
        LDAQ(afQ, Ac, 3);
        MMA3(2, afP);
        MMA3(3, afQ);
        WAIT_VM0();
        BAR();
    }

    float bv[3];
#pragma unroll
    for (int n = 0; n < 3; n++) bv[n] = bias[n0 + wn * 48 + n * 16 + lr];
#pragma unroll
    for (int mm = 0; mm < 8; mm++)
#pragma unroll
        for (int n = 0; n < 3; n++)
#pragma unroll
            for (int jj = 0; jj < 4; jj++) {
                const size_t row = m0 + wm * 128 + mm * 16 + ls * 4 + jj;
                const size_t col = n0 + wn * 48 + n * 16 + lr;
                C[row * N + col] = f2b(acc[mm][jj >= 0 ? n : n][jj] + bv[n]);
            }
}

// ---------------- RoPE on Q,K only (pow-2 indexing) ----------------
__global__ __launch_bounds__(256) void rope_qk(const bf16_t* __restrict__ qkv,
                                               const int* __restrict__ pos_ids,
                                               bf16_t* __restrict__ Qo,
                                               bf16_t* __restrict__ Ko) {
    const size_t gid = (size_t)blockIdx.x * 256 + threadIdx.x;
    const int d8 = (int)(gid & 15);
    const size_t t1 = gid >> 4;
    const int which = (int)(t1 & 1);
    const size_t t2 = t1 >> 1;
    const int nh = (int)(t2 & 15);
    const size_t bs = t2 >> 4;                  // b*S + s
    const int s = (int)(bs & (S_ - 1));
    const int b = (int)(bs >> 11);

    const bf16_t* src = qkv + bs * (3 * H_) + nh * 384 + which * 128 + d8 * 8;
    bf16x8 xv = *(const bf16x8*)src;
    const bf16_t* xu = (const bf16_t*)&xv;

    float xf[8];
#pragma unroll
    for (int i = 0; i < 8; i++) xf[i] = b2f(xu[i]);
    const int d0 = d8 * 8;
    if (d0 < 32) {
        const float pos = (float)pos_ids[bs];
        bf16x8 yv = *(const bf16x8*)(src + ((d0 < 16) ? 16 : -16));
        const bf16_t* yu = (const bf16_t*)&yv;
#pragma unroll
        for (int i = 0; i < 8; i++) {
            const int d = d0 + i;
            const float th = pos * exp2f(-(float)(d & 15) * L2B16);
            const float c = cosf(th), sn = sinf(th);
            const float rot = (d < 16) ? -b2f(yu[i]) : b2f(yu[i]);
            xf[i] = xf[i] * c + rot * sn;
        }
    }
    bf16_t ou[8];
#pragma unroll
    for (int i = 0; i < 8; i++) ou[i] = f2b(xf[i]);
    bf16_t* dst = ((which == 0) ? Qo : Ko) + ((size_t)(b * NH_ + nh) * S_ + s) * HS_ + d0;
    *(bf16x8*)dst = *(const bf16x8*)ou;
}

// ---------------- V transpose: (b,s,h,d) -> (bh, d, s), LDS-tiled ----------
__global__ __launch_bounds__(256) void vxpose(const bf16_t* __restrict__ qkv,
                                              bf16_t* __restrict__ Vt) {
    __shared__ bf16_t t[128][130];
    const int bh = (int)blockIdx.x >> 4;
    const int s0 = ((int)blockIdx.x & 15) << 7;
    const int b = bh >> 4, h = bh & 15;
    const int tid = threadIdx.x;

    const int dc = tid & 15, sl = tid >> 4;
    const bf16_t* src = qkv + ((size_t)b * S_ + s0) * (3 * H_) + h * 384 + 256 + dc * 8;
#pragma unroll
    for (int c = 0; c < 8; c++) {
        const int s = sl + c * 16;
        bf16x8 v = *(const bf16x8*)(src + (size_t)s * (3 * H_));
        *(bf16x8*)&t[s][dc * 8] = v;
    }
    __syncthreads();
    const int sc = tid & 15, dl = tid >> 4;
    bf16_t* dst = Vt + ((size_t)bh * HS_) * S_ + s0 + sc * 8;
#pragma unroll
    for (int c = 0; c < 8; c++) {
        const int d = dl + c * 16;
        bf16_t o[8];
#pragma unroll
        for (int i = 0; i < 8; i++) o[i] = t[sc * 8 + i][d];
        *(bf16x8*)(dst + (size_t)d * S_) = *(const bf16x8*)o;
    }
}

// ---------------- causal flash attention (r8 structure, best known) ---------
__device__ __forceinline__ void attn_stage(bf16_t* Kd, bf16_t* Vd,
                                           const bf16_t* Kg, const bf16_t* Vg,
                                           int kv0, int wid, int lane) {
#pragma unroll
    for (int jj = 0; jj < 4; jj++) {
        const int c = (wid << 2) + jj;
        const int rk = (c << 2) + (lane >> 4);        // K row 0..63
        async16(Kd + c * 512,
                Kg + (size_t)(kv0 + rk) * HS_ + (((lane & 15) ^ (rk & 7)) << 3));
        const int rv = (c << 3) + (lane >> 3);        // V^T row 0..127
        async16(Vd + c * 512,
                Vg + (size_t)rv * S_ + kv0 + (((lane & 7) ^ (rv & 7)) << 3));
    }
}

__global__ __launch_bounds__(256) void attn_fwd(const bf16_t* __restrict__ Q,
                                                const bf16_t* __restrict__ Kv,
                                                const bf16_t* __restrict__ Vt,
                                                const float* __restrict__ amask,
                                                bf16_t* __restrict__ ctx) {
    __shared__ __align__(16) bf16_t Ks[2][64 * 128];
    __shared__ __align__(16) bf16_t Vs[2][128 * 64];
    __shared__ __align__(16) bf16_t Ps[4][16 * 72];

    const int id = (int)(blockIdx.x + (blockIdx.y << 4));     // 0..511
    const int wg = ((id & 7) << 6) + (id >> 3);               // XCD-bijective
    const int pair = wg & 15;
    const int bh = wg >> 4;
    const int b = bh >> 4, h = bh & 15;
    const int tid = threadIdx.x, wid = tid >> 6, lane = tid & 63;
    const int lr = lane & 15, ls = lane >> 4;
    const float* am = amask + (size_t)b * S_;
    const bf16_t* Kg = Kv + (size_t)bh * S_ * HS_;
    const bf16_t* Vg = Vt + (size_t)bh * HS_ * S_;

#pragma unroll 1
    for (int half = 0; half < 2; ++half) {
        const int qt = half ? pair : (31 - pair);
        const int q0 = qt << 6;
        const int qrow = q0 + wid * 16 + lr;     // this lane's q-row

        bf16x8 qf[4];
        const bf16_t* qp = Q + ((size_t)bh * S_ + qrow) * HS_;
#pragma unroll
        for (int dk = 0; dk < 4; dk++) qf[dk] = *(const bf16x8*)(qp + dk * 32 + ls * 8);

        float mrun = -3.0e38f, lrun = 0.f;
        f32x4 oacc[8];
#pragma unroll
        for (int dt = 0; dt < 8; dt++) oacc[dt] = (f32x4){0.f, 0.f, 0.f, 0.f};

        attn_stage(Ks[0], Vs[0], Kg, Vg, 0, wid, lane);

#pragma unroll 1
        for (int step = 0; step <= qt; ++step) {
            const int cur = step & 1;
            const int kv0 = step << 6;
            if (step < qt) {
                attn_stage(Ks[cur ^ 1], Vs[cur ^ 1], Kg, Vg, (step + 1) << 6, wid, lane);
                WAIT_VM8();
            } else {
                WAIT_VM0();
            }
            BAR();

            // swapped QK^T
            f32x4 sacc[4];
#pragma unroll
            for (int t = 0; t < 4; t++) sacc[t] = (f32x4){0.f, 0.f, 0.f, 0.f};
#pragma unroll
            for (int t = 0; t < 4; t++)
#pragma unroll
                for (int dk = 0; dk < 4; dk++) {
                    const int row = t * 16 + lr;
                    bf16x8 kf = *(const bf16x8*)
                        &Ks[cur][row * 128 + (((dk * 4 + ls) ^ (row & 7)) << 3)];
                    sacc[t] = mfma16(kf, qf[dk], sacc[t]);
                }

            const bool diag = (step == qt);
            float sv[4][4];
            float rmax = -3.0e38f;
#pragma unroll
            for (int t = 0; t < 4; t++) {
                const float4 amv = *(const float4*)&am[kv0 + t * 16 + ls * 4];
                const float amj[4] = { amv.x, amv.y, amv.z, amv.w };
#pragma unroll
                for (int j = 0; j < 4; j++) {
                    const int kvp = kv0 + t * 16 + ls * 4 + j;
                    float v = sacc[t][j] * NORM_ + amj[j];
                    if (diag && kvp > qrow) v = -3.0e38f;
                    sv[t][j] = v;
                    rmax = fmaxf(rmax, v);
                }
            }
            rmax = fmaxf(rmax, __shfl_xor(rmax, 16));
            rmax = fmaxf(rmax, __shfl_xor(rmax, 32));

            // rescale only when not an exact identity (rmax > mrun somewhere)
            if (!__all((int)(rmax <= mrun))) {
                const float mnew = fmaxf(mrun, rmax);
                const float sc = __expf(mrun - mnew);
                lrun *= sc;
                mrun = mnew;
                float scb[4];
#pragma unroll
                for (int j = 0; j < 4; j++) scb[j] = __shfl(sc, ls * 4 + j);
#pragma unroll
                for (int dt = 0; dt < 8; dt++)
#pragma unroll
                    for (int j = 0; j < 4; j++) oacc[dt][j] *= scb[j];
            }

            // P = exp(S - mrun), f2b-packed pairs -> ds_write_b32
            float psum = 0.f;
#pragma unroll
            for (int t = 0; t < 4; t++) {
                const float p0 = __expf(sv[t][0] - mrun);
                const float p1 = __expf(sv[t][1] - mrun);
                const float p2 = __expf(sv[t][2] - mrun);
                const float p3 = __expf(sv[t][3] - mrun);
                psum += (p0 + p1) + (p2 + p3);
                const unsigned pk0 = (unsigned)f2b(p0) | ((unsigned)f2b(p1) << 16);
                const unsigned pk1 = (unsigned)f2b(p2) | ((unsigned)f2b(p3) << 16);
                *(unsigned*)&Ps[wid][lr * 72 + t * 16 + ls * 4]     = pk0;
                *(unsigned*)&Ps[wid][lr * 72 + t * 16 + ls * 4 + 2] = pk1;
            }
            psum += __shfl_xor(psum, 16);
            psum += __shfl_xor(psum, 32);
            lrun += psum;

            bf16x8 pf[2];
#pragma unroll
            for (int hh = 0; hh < 2; hh++)
                pf[hh] = *(const bf16x8*)&Ps[wid][lr * 72 + hh * 32 + ls * 8];
#pragma unroll
            for (int dt = 0; dt < 8; dt++)
#pragma unroll
                for (int hh = 0; hh < 2; hh++) {
                    const int vrow = dt * 16 + lr;
                    bf16x8 vf = *(const bf16x8*)
                        &Vs[cur][vrow * 64 + (((hh * 4 + ls) ^ (vrow & 7)) << 3)];
                    oacc[dt] = mfma16(pf[hh], vf, oacc[dt]);
                }
            BAR();
        }

        const float inv = 1.0f / lrun;           // q=lr layout
        float invj[4];
#pragma unroll
        for (int j = 0; j < 4; j++) invj[j] = __shfl(inv, ls * 4 + j);
#pragma unroll
        for (int j = 0; j < 4; j++) {
            bf16_t* dst = ctx + ((size_t)b * S_ + q0 + wid * 16 + ls * 4 + j) * H_ + h * HS_;
#pragma unroll
            for (int dt = 0; dt < 8; dt++) dst[dt * 16 + lr] = f2b(oacc[dt][j] * invj[j]);
        }
    }
}

extern "C" void kernel_launch(void* const* d_in, const int* in_sizes, int n_in,
                              void* d_out, int out_size, void* d_ws, size_t ws_size,
                              hipStream_t stream) {
    const float* hs   = (const float*)d_in[0];
    const float* am   = (const float*)d_in[1];
    const int*   pos  = (const int*)d_in[2];
    const float* Wqkv = (const float*)d_in[3];
    const float* bqkv = (const float*)d_in[4];
    const float* Wd   = (const float*)d_in[5];
    const float* bd   = (const float*)d_in[6];
    float* out = (float*)d_out;
    char*  ws  = (char*)d_ws;

    const size_t MB = 1024 * 1024;
    bf16_t* X    = (bf16_t*)(ws);              // 16 MB (reused as ctx)
    bf16_t* WqT  = (bf16_t*)(ws + 16 * MB);    // 24 MB
    bf16_t* WdT  = (bf16_t*)(ws + 40 * MB);    // 8 MB
    bf16_t* QKVb = (bf16_t*)(ws + 48 * MB);    // 48 MB
    bf16_t* Qb   = (bf16_t*)(ws + 96 * MB);    // 16 MB
    bf16_t* Kb   = (bf16_t*)(ws + 112 * MB);   // 16 MB
    bf16_t* Vtb  = (bf16_t*)(ws + 128 * MB);   // 16 MB
    bf16_t* ctx  = X;

    cvt_bf16<<<4096, 256, 0, stream>>>(hs, X);
    transpose_cvt<<<dim3(6144 / 64, 2048 / 64), 256, 0, stream>>>(Wqkv, WqT, 2048, 6144);
    transpose_cvt<<<dim3(2048 / 64, 2048 / 64), 256, 0, stream>>>(Wd, WdT, 2048, 2048);
    gemm_qkv<<<dim3(32, 16), 512, 0, stream>>>(X, WqT, bqkv, QKVb, 4096, 6144, 2048);
    rope_qk<<<8192, 256, 0, stream>>>(QKVb, pos, Qb, Kb);
    vxpose<<<512, 256, 0, stream>>>(QKVb, Vtb);
    attn_fwd<<<dim3(16, 32), 256, 0, stream>>>(Qb, Kb, Vtb, am, ctx);
    gemm_bias<0><<<dim3(16, 32), 256, 0, stream>>>(ctx, WdT, bd, out, 4096, 2048, 2048);
}

// Round 14
// 297.607 us; speedup vs baseline: 1.2963x; 1.0427x over previous
//
#include <hip/hip_runtime.h>

#define B_   2
#define S_   2048
#define H_   2048
#define NH_  16
#define HS_  128
#define NORM_ 0.08838834764831845f          // 128^-0.5
#define L2B16 0.8304820237218407f           // log2(10000)/16

typedef unsigned short bf16_t;
typedef __bf16 bf16x8 __attribute__((ext_vector_type(8)));
typedef float  f32x4  __attribute__((ext_vector_type(4)));

__device__ __forceinline__ float b2f(bf16_t u) {
    return __uint_as_float(((unsigned int)u) << 16);
}
__device__ __forceinline__ bf16_t f2b(float f) {
    unsigned int x = __float_as_uint(f);
    x += 0x7fffu + ((x >> 16) & 1u);        // round-to-nearest-even
    return (bf16_t)(x >> 16);
}

__device__ __forceinline__ void async16(bf16_t* lds, const bf16_t* g) {
    __builtin_amdgcn_global_load_lds(
        (const __attribute__((address_space(1))) void*)g,
        (__attribute__((address_space(3))) void*)lds, 16, 0, 0);
}

__device__ __forceinline__ f32x4 mfma16(bf16x8 a, bf16x8 b, f32x4 c) {
    return __builtin_amdgcn_mfma_f32_16x16x32_bf16(a, b, c, 0, 0, 0);
}

#define BAR()        asm volatile("s_barrier" ::: "memory")
#define WAIT_VM0()   asm volatile("s_waitcnt vmcnt(0)" ::: "memory")
#define WAIT_VM8()   asm volatile("s_waitcnt vmcnt(8)" ::: "memory")

// ---------------- f32 -> bf16 convert (8 elems/thread) ----------------
__global__ __launch_bounds__(256) void cvt_bf16(const float* __restrict__ in,
                                                bf16_t* __restrict__ out) {
    const size_t i = (size_t)blockIdx.x * 256 + threadIdx.x;
    const float4* p = (const float4*)in + i * 2;
    float4 a = p[0], b = p[1];
    bf16_t o[8] = { f2b(a.x), f2b(a.y), f2b(a.z), f2b(a.w),
                    f2b(b.x), f2b(b.y), f2b(b.z), f2b(b.w) };
    *((bf16x8*)out + i) = *(const bf16x8*)o;
}

// ---------------- W (KxN f32) -> W^T (NxK bf16), 64x64 tiles, vectorized ----
__global__ __launch_bounds__(256) void transpose_cvt(const float* __restrict__ W,
                                                     bf16_t* __restrict__ WT,
                                                     int K, int N) {
    __shared__ float t[64][65];
    const int n0 = blockIdx.x * 64, k0 = blockIdx.y * 64;
    const int tid = threadIdx.x;
    const int cx = tid & 15, r0 = tid >> 4;
#pragma unroll
    for (int p = 0; p < 4; p++) {
        const int row = p * 16 + r0;
        const float4 v = *(const float4*)&W[(size_t)(k0 + row) * N + n0 + cx * 4];
        t[row][cx * 4 + 0] = v.x;
        t[row][cx * 4 + 1] = v.y;
        t[row][cx * 4 + 2] = v.z;
        t[row][cx * 4 + 3] = v.w;
    }
    __syncthreads();
    const int n = tid >> 2, k8 = tid & 3;
#pragma unroll
    for (int p = 0; p < 2; p++) {
        const int kk = (k8 + p * 4) * 8;
        bf16_t o[8];
#pragma unroll
        for (int i = 0; i < 8; i++) o[i] = f2b(t[kk + i][n]);
        *(bf16x8*)&WT[(size_t)(n0 + n) * K + k0 + kk] = *(const bf16x8*)o;
    }
}

// ---------------- 128x128 2-phase GEMM (dense), XCD 8x8-tiled --------------
template <int BF16OUT>
__global__ __launch_bounds__(256) void gemm_bias(const bf16_t* __restrict__ A,
                                                 const bf16_t* __restrict__ BT,
                                                 const float* __restrict__ bias,
                                                 void* __restrict__ Cv,
                                                 int M, int N, int K) {
    __shared__ __align__(16) bf16_t As[128 * 32];
    __shared__ __align__(16) bf16_t Bs[128 * 32];
    const int id  = (int)(blockIdx.y * gridDim.x + blockIdx.x);
    const int xcd = id & 7, j = id >> 3;
    const int bx  = (xcd & 1) * 8 + (j & 7);       // 0..15
    const int by  = (xcd >> 1) * 8 + (j >> 3);     // 0..31
    const int tid = threadIdx.x;
    const int wid = tid >> 6, lane = tid & 63;
    const int lr = lane & 15, ls = lane >> 4;
    const int wr = wid >> 1, wc = wid & 1;
    const size_t m0 = (size_t)by * 128, n0 = (size_t)bx * 128;

    f32x4 acc[4][4];
#pragma unroll
    for (int m = 0; m < 4; m++)
#pragma unroll
        for (int n = 0; n < 4; n++) acc[m][n] = (f32x4){0.f, 0.f, 0.f, 0.f};

    const int srow = lane >> 2, sk = (lane & 3) * 8;

    for (int k0 = 0; k0 < K; k0 += 32) {
        __syncthreads();
#pragma unroll
        for (int jj = 0; jj < 2; jj++) {
            const int rr = (wid * 2 + jj) * 16 + srow;
            async16(As + (wid * 2 + jj) * 512, A + (m0 + rr) * K + k0 + sk);
            async16(Bs + (wid * 2 + jj) * 512, BT + (n0 + rr) * K + k0 + sk);
        }
        __syncthreads();
        bf16x8 af[4], bfr[4];
#pragma unroll
        for (int m = 0; m < 4; m++)
            af[m] = *(const bf16x8*)&As[(wr * 64 + m * 16 + lr) * 32 + ls * 8];
#pragma unroll
        for (int n = 0; n < 4; n++)
            bfr[n] = *(const bf16x8*)&Bs[(wc * 64 + n * 16 + lr) * 32 + ls * 8];
#pragma unroll
        for (int m = 0; m < 4; m++)
#pragma unroll
            for (int n = 0; n < 4; n++)
                acc[m][n] = mfma16(af[m], bfr[n], acc[m][n]);
    }

    float bv[4];
#pragma unroll
    for (int n = 0; n < 4; n++) bv[n] = bias[n0 + wc * 64 + n * 16 + lr];
#pragma unroll
    for (int m = 0; m < 4; m++)
#pragma unroll
        for (int n = 0; n < 4; n++)
#pragma unroll
            for (int jj = 0; jj < 4; jj++) {
                const size_t row = m0 + wr * 64 + m * 16 + ls * 4 + jj;
                const size_t col = n0 + wc * 64 + n * 16 + lr;
                const float v = acc[m][n][jj] + bv[n];
                if (BF16OUT) ((bf16_t*)Cv)[row * N + col] = f2b(v);
                else         ((float*)Cv)[row * N + col] = v;
            }
}

// ---------------- shared staging helper (512-thread blocks) ----------------
__device__ __forceinline__ void st512(bf16_t* lds, const bf16_t* g,
                                      int K, int part, int tid) {
    const int idx = part * 512 + tid;
    const int row = idx >> 3, slot = idx & 7;
    async16(lds + idx * 8, g + (size_t)row * K + ((slot ^ (row & 7)) << 3));
}

#define LDAQ(dst, ab, q) do {                                                  \
    _Pragma("unroll")                                                          \
    for (int m = 0; m < 2; m++)                                                \
        _Pragma("unroll")                                                      \
        for (int ks = 0; ks < 2; ks++) {                                       \
            const int r = wm * 128 + (q) * 32 + m * 16 + lr;                   \
            dst[m][ks] = *(const bf16x8*)                                      \
                &(ab)[r * 64 + (((ks * 4 + ls) ^ (r & 7)) << 3)];              \
        }                                                                      \
} while (0)

#define LDB2(bb) do {                                                          \
    _Pragma("unroll")                                                          \
    for (int n = 0; n < 2; n++)                                                \
        _Pragma("unroll")                                                      \
        for (int ks = 0; ks < 2; ks++) {                                       \
            const int r = wn * 32 + n * 16 + lr;                               \
            bfr[n][ks] = *(const bf16x8*)                                      \
                &(bb)[r * 64 + (((ks * 4 + ls) ^ (r & 7)) << 3)];              \
        }                                                                      \
} while (0)

#define MMA2(q, src) do {                                                      \
    __builtin_amdgcn_s_setprio(1);                                             \
    _Pragma("unroll")                                                          \
    for (int ks = 0; ks < 2; ks++)                                             \
        _Pragma("unroll")                                                      \
        for (int n = 0; n < 2; n++)                                            \
            _Pragma("unroll")                                                  \
            for (int m = 0; m < 2; m++)                                        \
                acc[(q) * 2 + m][n] =                                          \
                    mfma16(src[m][ks], bfr[n][ks], acc[(q) * 2 + m][n]);       \
    __builtin_amdgcn_s_setprio(0);                                             \
} while (0)

// ---------------- fused QKV GEMM: 256x128 tile + RoPE/scatter epilogue ------
// grid (48,16) = 768 blocks = 3 exact rounds. Column tile bx is exactly one
// (nh = bx/3, which = bx%3) 128-dim slice. Per-wave N=32 (2 frags): RoPE pair
// (d, d+16) = (n=0, n=1) of wn==0 lives in the SAME thread. Epilogue writes
// Q/K (row-major per bh, 2B lane-merged) and V^T (8B stores), no QKV buffer.
__global__ __launch_bounds__(512, 2) void gemm_qkv_fused(
        const bf16_t* __restrict__ A, const bf16_t* __restrict__ BT,
        const float* __restrict__ bias, const int* __restrict__ pos_ids,
        bf16_t* __restrict__ Qo, bf16_t* __restrict__ Ko,
        bf16_t* __restrict__ Vt, int M, int N, int K) {
    __shared__ __align__(16) bf16_t As[2][256 * 64];
    __shared__ __align__(16) bf16_t Bs[2][128 * 64];

    const int id  = (int)(blockIdx.y * gridDim.x + blockIdx.x);   // 0..767
    const int xcd = id & 7, jj = id >> 3;                         // jj 0..95
    const int bx  = (xcd & 3) * 12 + (jj % 12);                   // 0..47
    const int by  = (xcd >> 2) * 8 + (jj / 12);                   // 0..15

    const int tid = threadIdx.x;
    const int wid = tid >> 6, lane = tid & 63;
    const int lr = lane & 15, ls = lane >> 4;
    const int wm = wid >> 2, wn = wid & 3;
    const size_t m0 = (size_t)by * 256, n0 = (size_t)bx * 128;

    const bf16_t* Ab = A + m0 * K;
    const bf16_t* Bb = BT + n0 * K;

    f32x4 acc[8][2];
#pragma unroll
    for (int m = 0; m < 8; m++)
#pragma unroll
        for (int n = 0; n < 2; n++) acc[m][n] = (f32x4){0.f, 0.f, 0.f, 0.f};
    bf16x8 bfr[2][2];
    bf16x8 afP[2][2], afQ[2][2];

#pragma unroll
    for (int p = 0; p < 4; p++) st512(As[0], Ab, K, p, tid);
#pragma unroll
    for (int p = 0; p < 2; p++) st512(Bs[0], Bb, K, p, tid);
    WAIT_VM0();
    BAR();

    const int nt = K >> 6;
#pragma unroll 1
    for (int i = 0; i < nt; ++i) {
        const int c = i & 1;
        const bf16_t* Ac = As[c];
        const bf16_t* Bc = Bs[c];
        if (i + 1 < nt) {
            const size_t ko = (size_t)(i + 1) * 64;
            bf16_t* Ad = As[c ^ 1];
            bf16_t* Bd = Bs[c ^ 1];
#pragma unroll
            for (int p = 0; p < 4; p++) st512(Ad, Ab + ko, K, p, tid);
#pragma unroll
            for (int p = 0; p < 2; p++) st512(Bd, Bb + ko, K, p, tid);
        }
        __builtin_amdgcn_sched_barrier(0);
        LDAQ(afP, Ac, 0);
        LDB2(Bc);
        LDAQ(afQ, Ac, 1);
        MMA2(0, afP);
        LDAQ(afP, Ac, 2);
        MMA2(1, afQ);
        LDAQ(afQ, Ac, 3);
        MMA2(2, afP);
        MMA2(3, afQ);
        WAIT_VM0();
        BAR();
    }

    // -------- epilogue: bias + RoPE + scatter --------
    const int which = bx % 3;                    // 0=Q 1=K 2=V
    const int nh    = bx / 3;
    float bv[2];
#pragma unroll
    for (int n = 0; n < 2; n++) bv[n] = bias[n0 + wn * 32 + n * 16 + lr];

    if (which == 2) {                            // V -> V^T[bh][d][s]
#pragma unroll
        for (int mm = 0; mm < 8; mm++) {
            const int row0 = (int)m0 + wm * 128 + mm * 16 + ls * 4;
            const int b = row0 >> 11, s = row0 & 2047;
            const size_t bh = (size_t)(b * NH_ + nh);
#pragma unroll
            for (int n = 0; n < 2; n++) {
                const int d = wn * 32 + n * 16 + lr;
                bf16_t o[4];
#pragma unroll
                for (int j = 0; j < 4; j++) o[j] = f2b(acc[mm][n][j] + bv[n]);
                *(uint2*)&Vt[(bh * HS_ + d) * S_ + s] = *(const uint2*)o;
            }
        }
    } else {
        bf16_t* O = which ? Ko : Qo;
#pragma unroll
        for (int mm = 0; mm < 8; mm++) {
            const int row0 = (int)m0 + wm * 128 + mm * 16 + ls * 4;
            const int b = row0 >> 11;
            const size_t bh = (size_t)(b * NH_ + nh);
#pragma unroll
            for (int j = 0; j < 4; j++) {
                const int row = row0 + j;
                const int s = row & 2047;
                float a0 = acc[mm][0][j] + bv[0];
                float a1 = acc[mm][1][j] + bv[1];
                if (wn == 0) {                   // d = lr, d+16 = pair
                    const float pos = (float)pos_ids[row];
                    const float th = pos * __builtin_exp2f(-(float)lr * L2B16);
                    const float c = __cosf(th), sn = __sinf(th);
                    const float o0 = a0 * c - a1 * sn;
                    const float o1 = a1 * c + a0 * sn;
                    a0 = o0; a1 = o1;
                }
                bf16_t* dst = O + (bh * S_ + s) * HS_ + wn * 32 + lr;
                dst[0]  = f2b(a0);
                dst[16] = f2b(a1);
            }
        }
    }
}

// ---------------- causal flash attention (r8 structure, best known) ---------
__device__ __forceinline__ void attn_stage(bf16_t* Kd, bf16_t* Vd,
                                           const bf16_t* Kg, const bf16_t* Vg,
                                           int kv0, int wid, int lane) {
#pragma unroll
    for (int jj = 0; jj < 4; jj++) {
        const int c = (wid << 2) + jj;
        const int rk = (c << 2) + (lane >> 4);        // K row 0..63
        async16(Kd + c * 512,
                Kg + (size_t)(kv0 + rk) * HS_ + (((lane & 15) ^ (rk & 7)) << 3));
        const int rv = (c << 3) + (lane >> 3);        // V^T row 0..127
        async16(Vd + c * 512,
                Vg + (size_t)rv * S_ + kv0 + (((lane & 7) ^ (rv & 7)) << 3));
    }
}

__global__ __launch_bounds__(256) void attn_fwd(const bf16_t* __restrict__ Q,
                                                const bf16_t* __restrict__ Kv,
                                                const bf16_t* __restrict__ Vt,
                                                const float* __restrict__ amask,
                                                bf16_t* __restrict__ ctx) {
    __shared__ __align__(16) bf16_t Ks[2][64 * 128];
    __shared__ __align__(16) bf16_t Vs[2][128 * 64];
    __shared__ __align__(16) bf16_t Ps[4][16 * 72];

    const int id = (int)(blockIdx.x + (blockIdx.y << 4));     // 0..511
    const int wg = ((id & 7) << 6) + (id >> 3);               // XCD-bijective
    const int pair = wg & 15;
    const int bh = wg >> 4;
    const int b = bh >> 4, h = bh & 15;
    const int tid = threadIdx.x, wid = tid >> 6, lane = tid & 63;
    const int lr = lane & 15, ls = lane >> 4;
    const float* am = amask + (size_t)b * S_;
    const bf16_t* Kg = Kv + (size_t)bh * S_ * HS_;
    const bf16_t* Vg = Vt + (size_t)bh * HS_ * S_;

#pragma unroll 1
    for (int half = 0; half < 2; ++half) {
        const int qt = half ? pair : (31 - pair);
        const int q0 = qt << 6;
        const int qrow = q0 + wid * 16 + lr;     // this lane's q-row

        bf16x8 qf[4];
        const bf16_t* qp = Q + ((size_t)bh * S_ + qrow) * HS_;
#pragma unroll
        for (int dk = 0; dk < 4; dk++) qf[dk] = *(const bf16x8*)(qp + dk * 32 + ls * 8);

        float mrun = -3.0e38f, lrun = 0.f;
        f32x4 oacc[8];
#pragma unroll
        for (int dt = 0; dt < 8; dt++) oacc[dt] = (f32x4){0.f, 0.f, 0.f, 0.f};

        attn_stage(Ks[0], Vs[0], Kg, Vg, 0, wid, lane);

#pragma unroll 1
        for (int step = 0; step <= qt; ++step) {
            const int cur = step & 1;
            const int kv0 = step << 6;
            if (step < qt) {
                attn_stage(Ks[cur ^ 1], Vs[cur ^ 1], Kg, Vg, (step + 1) << 6, wid, lane);
                WAIT_VM8();
            } else {
                WAIT_VM0();
            }
            BAR();

            // swapped QK^T
            f32x4 sacc[4];
#pragma unroll
            for (int t = 0; t < 4; t++) sacc[t] = (f32x4){0.f, 0.f, 0.f, 0.f};
#pragma unroll
            for (int t = 0; t < 4; t++)
#pragma unroll
                for (int dk = 0; dk < 4; dk++) {
                    const int row = t * 16 + lr;
                    bf16x8 kf = *(const bf16x8*)
                        &Ks[cur][row * 128 + (((dk * 4 + ls) ^ (row & 7)) << 3)];
                    sacc[t] = mfma16(kf, qf[dk], sacc[t]);
                }

            const bool diag = (step == qt);
            float sv[4][4];
            float rmax = -3.0e38f;
#pragma unroll
            for (int t = 0; t < 4; t++) {
                const float4 amv = *(const float4*)&am[kv0 + t * 16 + ls * 4];
                const float amj[4] = { amv.x, amv.y, amv.z, amv.w };
#pragma unroll
                for (int j = 0; j < 4; j++) {
                    const int kvp = kv0 + t * 16 + ls * 4 + j;
                    float v = sacc[t][j] * NORM_ + amj[j];
                    if (diag && kvp > qrow) v = -3.0e38f;
                    sv[t][j] = v;
                    rmax = fmaxf(rmax, v);
                }
            }
            rmax = fmaxf(rmax, __shfl_xor(rmax, 16));
            rmax = fmaxf(rmax, __shfl_xor(rmax, 32));

            if (!__all((int)(rmax <= mrun))) {
                const float mnew = fmaxf(mrun, rmax);
                const float sc = __expf(mrun - mnew);
                lrun *= sc;
                mrun = mnew;
                float scb[4];
#pragma unroll
                for (int j = 0; j < 4; j++) scb[j] = __shfl(sc, ls * 4 + j);
#pragma unroll
                for (int dt = 0; dt < 8; dt++)
#pragma unroll
                    for (int j = 0; j < 4; j++) oacc[dt][j] *= scb[j];
            }

            float psum = 0.f;
#pragma unroll
            for (int t = 0; t < 4; t++) {
                const float p0 = __expf(sv[t][0] - mrun);
                const float p1 = __expf(sv[t][1] - mrun);
                const float p2 = __expf(sv[t][2] - mrun);
                const float p3 = __expf(sv[t][3] - mrun);
                psum += (p0 + p1) + (p2 + p3);
                const unsigned pk0 = (unsigned)f2b(p0) | ((unsigned)f2b(p1) << 16);
                const unsigned pk1 = (unsigned)f2b(p2) | ((unsigned)f2b(p3) << 16);
                *(unsigned*)&Ps[wid][lr * 72 + t * 16 + ls * 4]     = pk0;
                *(unsigned*)&Ps[wid][lr * 72 + t * 16 + ls * 4 + 2] = pk1;
            }
            psum += __shfl_xor(psum, 16);
            psum += __shfl_xor(psum, 32);
            lrun += psum;

            bf16x8 pf[2];
#pragma unroll
            for (int hh = 0; hh < 2; hh++)
                pf[hh] = *(const bf16x8*)&Ps[wid][lr * 72 + hh * 32 + ls * 8];
#pragma unroll
            for (int dt = 0; dt < 8; dt++)
#pragma unroll
                for (int hh = 0; hh < 2; hh++) {
                    const int vrow = dt * 16 + lr;
                    bf16x8 vf = *(const bf16x8*)
                        &Vs[cur][vrow * 64 + (((hh * 4 + ls) ^ (vrow & 7)) << 3)];
                    oacc[dt] = mfma16(pf[hh], vf, oacc[dt]);
                }
            BAR();
        }

        const float inv = 1.0f / lrun;           // q=lr layout
        float invj[4];
#pragma unroll
        for (int j = 0; j < 4; j++) invj[j] = __shfl(inv, ls * 4 + j);
#pragma unroll
        for (int j = 0; j < 4; j++) {
            bf16_t* dst = ctx + ((size_t)b * S_ + q0 + wid * 16 + ls * 4 + j) * H_ + h * HS_;
#pragma unroll
            for (int dt = 0; dt < 8; dt++) dst[dt * 16 + lr] = f2b(oacc[dt][j] * invj[j]);
        }
    }
}

extern "C" void kernel_launch(void* const* d_in, const int* in_sizes, int n_in,
                              void* d_out, int out_size, void* d_ws, size_t ws_size,
                              hipStream_t stream) {
    const float* hs   = (const float*)d_in[0];
    const float* am   = (const float*)d_in[1];
    const int*   pos  = (const int*)d_in[2];
    const float* Wqkv = (const float*)d_in[3];
    const float* bqkv = (const float*)d_in[4];
    const float* Wd   = (const float*)d_in[5];
    const float* bd   = (const float*)d_in[6];
    float* out = (float*)d_out;
    char*  ws  = (char*)d_ws;

    const size_t MB = 1024 * 1024;
    bf16_t* X    = (bf16_t*)(ws);              // 16 MB (reused as ctx)
    bf16_t* WqT  = (bf16_t*)(ws + 16 * MB);    // 24 MB
    bf16_t* WdT  = (bf16_t*)(ws + 40 * MB);    // 8 MB
    bf16_t* Qb   = (bf16_t*)(ws + 48 * MB);    // 16 MB
    bf16_t* Kb   = (bf16_t*)(ws + 64 * MB);    // 16 MB
    bf16_t* Vtb  = (bf16_t*)(ws + 80 * MB);    // 16 MB
    bf16_t* ctx  = X;

    cvt_bf16<<<4096, 256, 0, stream>>>(hs, X);
    transpose_cvt<<<dim3(6144 / 64, 2048 / 64), 256, 0, stream>>>(Wqkv, WqT, 2048, 6144);
    transpose_cvt<<<dim3(2048 / 64, 2048 / 64), 256, 0, stream>>>(Wd, WdT, 2048, 2048);
    gemm_qkv_fused<<<dim3(48, 16), 512, 0, stream>>>(X, WqT, bqkv, pos,
                                                     Qb, Kb, Vtb, 4096, 6144, 2048);
    attn_fwd<<<dim3(16, 32), 256, 0, stream>>>(Qb, Kb, Vtb, am, ctx);
    gemm_bias<0><<<dim3(16, 32), 256, 0, stream>>>(ctx, WdT, bd, out, 4096, 2048, 2048);
}

// Round 15
// 294.065 us; speedup vs baseline: 1.3120x; 1.0120x over previous
//
#include <hip/hip_runtime.h>

#define B_   2
#define S_   2048
#define H_   2048
#define NH_  16
#define HS_  128
#define NORM_ 0.08838834764831845f          // 128^-0.5
#define L2B16 0.8304820237218407f           // log2(10000)/16

typedef unsigned short bf16_t;
typedef __bf16 bf16x8 __attribute__((ext_vector_type(8)));
typedef float  f32x4  __attribute__((ext_vector_type(4)));

__device__ __forceinline__ float b2f(bf16_t u) {
    return __uint_as_float(((unsigned int)u) << 16);
}
__device__ __forceinline__ bf16_t f2b(float f) {
    unsigned int x = __float_as_uint(f);
    x += 0x7fffu + ((x >> 16) & 1u);        // round-to-nearest-even
    return (bf16_t)(x >> 16);
}

__device__ __forceinline__ void async16(bf16_t* lds, const bf16_t* g) {
    __builtin_amdgcn_global_load_lds(
        (const __attribute__((address_space(1))) void*)g,
        (__attribute__((address_space(3))) void*)lds, 16, 0, 0);
}

__device__ __forceinline__ f32x4 mfma16(bf16x8 a, bf16x8 b, f32x4 c) {
    return __builtin_amdgcn_mfma_f32_16x16x32_bf16(a, b, c, 0, 0, 0);
}

#define BAR()        asm volatile("s_barrier" ::: "memory")
#define WAIT_VM0()   asm volatile("s_waitcnt vmcnt(0)" ::: "memory")
#define WAIT_VM8()   asm volatile("s_waitcnt vmcnt(8)" ::: "memory")

// ---------------- f32 -> bf16 convert (8 elems/thread) ----------------
__global__ __launch_bounds__(256) void cvt_bf16(const float* __restrict__ in,
                                                bf16_t* __restrict__ out) {
    const size_t i = (size_t)blockIdx.x * 256 + threadIdx.x;
    const float4* p = (const float4*)in + i * 2;
    float4 a = p[0], b = p[1];
    bf16_t o[8] = { f2b(a.x), f2b(a.y), f2b(a.z), f2b(a.w),
                    f2b(b.x), f2b(b.y), f2b(b.z), f2b(b.w) };
    *((bf16x8*)out + i) = *(const bf16x8*)o;
}

// ---------------- W (KxN f32) -> W^T (NxK bf16), 64x64 tiles, vectorized ----
__global__ __launch_bounds__(256) void transpose_cvt(const float* __restrict__ W,
                                                     bf16_t* __restrict__ WT,
                                                     int K, int N) {
    __shared__ float t[64][65];
    const int n0 = blockIdx.x * 64, k0 = blockIdx.y * 64;
    const int tid = threadIdx.x;
    const int cx = tid & 15, r0 = tid >> 4;
#pragma unroll
    for (int p = 0; p < 4; p++) {
        const int row = p * 16 + r0;
        const float4 v = *(const float4*)&W[(size_t)(k0 + row) * N + n0 + cx * 4];
        t[row][cx * 4 + 0] = v.x;
        t[row][cx * 4 + 1] = v.y;
        t[row][cx * 4 + 2] = v.z;
        t[row][cx * 4 + 3] = v.w;
    }
    __syncthreads();
    const int n = tid >> 2, k8 = tid & 3;
#pragma unroll
    for (int p = 0; p < 2; p++) {
        const int kk = (k8 + p * 4) * 8;
        bf16_t o[8];
#pragma unroll
        for (int i = 0; i < 8; i++) o[i] = f2b(t[kk + i][n]);
        *(bf16x8*)&WT[(size_t)(n0 + n) * K + k0 + kk] = *(const bf16x8*)o;
    }
}

// ---------------- 128x128 2-phase GEMM (dense), XCD 8x8-tiled --------------
template <int BF16OUT>
__global__ __launch_bounds__(256) void gemm_bias(const bf16_t* __restrict__ A,
                                                 const bf16_t* __restrict__ BT,
                                                 const float* __restrict__ bias,
                                                 void* __restrict__ Cv,
                                                 int M, int N, int K) {
    __shared__ __align__(16) bf16_t As[128 * 32];
    __shared__ __align__(16) bf16_t Bs[128 * 32];
    const int id  = (int)(blockIdx.y * gridDim.x + blockIdx.x);
    const int xcd = id & 7, j = id >> 3;
    const int bx  = (xcd & 1) * 8 + (j & 7);       // 0..15
    const int by  = (xcd >> 1) * 8 + (j >> 3);     // 0..31
    const int tid = threadIdx.x;
    const int wid = tid >> 6, lane = tid & 63;
    const int lr = lane & 15, ls = lane >> 4;
    const int wr = wid >> 1, wc = wid & 1;
    const size_t m0 = (size_t)by * 128, n0 = (size_t)bx * 128;

    f32x4 acc[4][4];
#pragma unroll
    for (int m = 0; m < 4; m++)
#pragma unroll
        for (int n = 0; n < 4; n++) acc[m][n] = (f32x4){0.f, 0.f, 0.f, 0.f};

    const int srow = lane >> 2, sk = (lane & 3) * 8;

    for (int k0 = 0; k0 < K; k0 += 32) {
        __syncthreads();
#pragma unroll
        for (int jj = 0; jj < 2; jj++) {
            const int rr = (wid * 2 + jj) * 16 + srow;
            async16(As + (wid * 2 + jj) * 512, A + (m0 + rr) * K + k0 + sk);
            async16(Bs + (wid * 2 + jj) * 512, BT + (n0 + rr) * K + k0 + sk);
        }
        __syncthreads();
        bf16x8 af[4], bfr[4];
#pragma unroll
        for (int m = 0; m < 4; m++)
            af[m] = *(const bf16x8*)&As[(wr * 64 + m * 16 + lr) * 32 + ls * 8];
#pragma unroll
        for (int n = 0; n < 4; n++)
            bfr[n] = *(const bf16x8*)&Bs[(wc * 64 + n * 16 + lr) * 32 + ls * 8];
#pragma unroll
        for (int m = 0; m < 4; m++)
#pragma unroll
            for (int n = 0; n < 4; n++)
                acc[m][n] = mfma16(af[m], bfr[n], acc[m][n]);
    }

    float bv[4];
#pragma unroll
    for (int n = 0; n < 4; n++) bv[n] = bias[n0 + wc * 64 + n * 16 + lr];
#pragma unroll
    for (int m = 0; m < 4; m++)
#pragma unroll
        for (int n = 0; n < 4; n++)
#pragma unroll
            for (int jj = 0; jj < 4; jj++) {
                const size_t row = m0 + wr * 64 + m * 16 + ls * 4 + jj;
                const size_t col = n0 + wc * 64 + n * 16 + lr;
                const float v = acc[m][n][jj] + bv[n];
                if (BF16OUT) ((bf16_t*)Cv)[row * N + col] = f2b(v);
                else         ((float*)Cv)[row * N + col] = v;
            }
}

// ---------------- shared staging helper (512-thread blocks) ----------------
__device__ __forceinline__ void st512(bf16_t* lds, const bf16_t* g,
                                      int K, int part, int tid) {
    const int idx = part * 512 + tid;
    const int row = idx >> 3, slot = idx & 7;
    async16(lds + idx * 8, g + (size_t)row * K + ((slot ^ (row & 7)) << 3));
}

#define LDAQ(dst, ab, q) do {                                                  \
    _Pragma("unroll")                                                          \
    for (int m = 0; m < 2; m++)                                                \
        _Pragma("unroll")                                                      \
        for (int ks = 0; ks < 2; ks++) {                                       \
            const int r = wm * 128 + (q) * 32 + m * 16 + lr;                   \
            dst[m][ks] = *(const bf16x8*)                                      \
                &(ab)[r * 64 + (((ks * 4 + ls) ^ (r & 7)) << 3)];              \
        }                                                                      \
} while (0)

#define LDB4(bb) do {                                                          \
    _Pragma("unroll")                                                          \
    for (int n = 0; n < 4; n++)                                                \
        _Pragma("unroll")                                                      \
        for (int ks = 0; ks < 2; ks++) {                                       \
            const int r = wn * 64 + n * 16 + lr;                               \
            bfr[n][ks] = *(const bf16x8*)                                      \
                &(bb)[r * 64 + (((ks * 4 + ls) ^ (r & 7)) << 3)];              \
        }                                                                      \
} while (0)

#define MMA4(q, src) do {                                                      \
    __builtin_amdgcn_s_setprio(1);                                             \
    _Pragma("unroll")                                                          \
    for (int ks = 0; ks < 2; ks++)                                             \
        _Pragma("unroll")                                                      \
        for (int n = 0; n < 4; n++)                                            \
            _Pragma("unroll")                                                  \
            for (int m = 0; m < 2; m++)                                        \
                acc[(q) * 2 + m][n] =                                          \
                    mfma16(src[m][ks], bfr[n][ks], acc[(q) * 2 + m][n]);       \
    __builtin_amdgcn_s_setprio(0);                                             \
} while (0)

// ---------------- fused QKV GEMM: 256x256 tile + RoPE/scatter epilogue ------
// grid (24,16) = 384 blocks. Column tile = TWO 128-dim (nh,which) slices:
// slice g = 2*bx + (wn>>1); which = g%3, nh = g/3. Per-wave 16-col block index
// within tile = (4*wn+n)&7; rot blocks {0,1} occur only at even wn as frags
// n=0,1 of the SAME thread (d=lr, d+16). 128KB LDS, acc[8][4] (~205 VGPR).
__global__ __launch_bounds__(512, 2) void gemm_qkv_fused(
        const bf16_t* __restrict__ A, const bf16_t* __restrict__ BT,
        const float* __restrict__ bias, const int* __restrict__ pos_ids,
        bf16_t* __restrict__ Qo, bf16_t* __restrict__ Ko,
        bf16_t* __restrict__ Vt, int M, int N, int K) {
    __shared__ __align__(16) bf16_t As[2][256 * 64];
    __shared__ __align__(16) bf16_t Bs[2][256 * 64];

    const int id  = (int)(blockIdx.y * gridDim.x + blockIdx.x);   // 0..383
    const int xcd = id & 7, jj = id >> 3;                         // jj 0..47
    const int bx  = (xcd & 3) * 6 + (jj % 6);                     // 0..23
    const int by  = (xcd >> 2) * 8 + (jj / 6);                    // 0..15

    const int tid = threadIdx.x;
    const int wid = tid >> 6, lane = tid & 63;
    const int lr = lane & 15, ls = lane >> 4;
    const int wm = wid >> 2, wn = wid & 3;
    const size_t m0 = (size_t)by * 256, n0 = (size_t)bx * 256;

    const bf16_t* Ab = A + m0 * K;
    const bf16_t* Bb = BT + n0 * K;

    f32x4 acc[8][4];
#pragma unroll
    for (int m = 0; m < 8; m++)
#pragma unroll
        for (int n = 0; n < 4; n++) acc[m][n] = (f32x4){0.f, 0.f, 0.f, 0.f};
    bf16x8 bfr[4][2];
    bf16x8 afP[2][2], afQ[2][2];

#pragma unroll
    for (int p = 0; p < 4; p++) st512(As[0], Ab, K, p, tid);
#pragma unroll
    for (int p = 0; p < 4; p++) st512(Bs[0], Bb, K, p, tid);
    WAIT_VM0();
    BAR();

    const int nt = K >> 6;
#pragma unroll 1
    for (int i = 0; i < nt; ++i) {
        const int c = i & 1;
        const bf16_t* Ac = As[c];
        const bf16_t* Bc = Bs[c];
        if (i + 1 < nt) {
            const size_t ko = (size_t)(i + 1) * 64;
            bf16_t* Ad = As[c ^ 1];
            bf16_t* Bd = Bs[c ^ 1];
#pragma unroll
            for (int p = 0; p < 4; p++) st512(Ad, Ab + ko, K, p, tid);
#pragma unroll
            for (int p = 0; p < 4; p++) st512(Bd, Bb + ko, K, p, tid);
        }
        __builtin_amdgcn_sched_barrier(0);
        LDAQ(afP, Ac, 0);
        LDB4(Bc);
        LDAQ(afQ, Ac, 1);
        MMA4(0, afP);
        LDAQ(afP, Ac, 2);
        MMA4(1, afQ);
        LDAQ(afQ, Ac, 3);
        MMA4(2, afP);
        MMA4(3, afQ);
        WAIT_VM0();
        BAR();
    }

    // -------- epilogue: bias + RoPE + scatter (two slices per tile) --------
    const int g     = bx * 2 + (wn >> 1);
    const int which = g % 3;                     // 0=Q 1=K 2=V
    const int nh    = g / 3;
    float bv[4];
#pragma unroll
    for (int n = 0; n < 4; n++) bv[n] = bias[n0 + wn * 64 + n * 16 + lr];

    if (which == 2) {                            // V -> V^T[bh][d][s]
#pragma unroll
        for (int mm = 0; mm < 8; mm++) {
            const int row0 = (int)m0 + wm * 128 + mm * 16 + ls * 4;
            const int b = row0 >> 11, s = row0 & 2047;
            const size_t bh = (size_t)(b * NH_ + nh);
#pragma unroll
            for (int n = 0; n < 4; n++) {
                const int d = ((4 * wn + n) & 7) * 16 + lr;
                bf16_t o[4];
#pragma unroll
                for (int j = 0; j < 4; j++) o[j] = f2b(acc[mm][n][j] + bv[n]);
                *(uint2*)&Vt[(bh * HS_ + d) * S_ + s] = *(const uint2*)o;
            }
        }
    } else {
        bf16_t* O = which ? Ko : Qo;
        const bool rot = ((wn & 1) == 0);        // blocks 0,1 of the slice
#pragma unroll
        for (int mm = 0; mm < 8; mm++) {
            const int row0 = (int)m0 + wm * 128 + mm * 16 + ls * 4;
            const int b = row0 >> 11;
            const size_t bh = (size_t)(b * NH_ + nh);
#pragma unroll
            for (int j = 0; j < 4; j++) {
                const int row = row0 + j;
                const int s = row & 2047;
                float av[4];
#pragma unroll
                for (int n = 0; n < 4; n++) av[n] = acc[mm][n][j] + bv[n];
                if (rot) {                       // d = lr (n=0), d+16 (n=1)
                    const float pos = (float)pos_ids[row];
                    const float th = pos * __builtin_exp2f(-(float)lr * L2B16);
                    const float c = __cosf(th), sn = __sinf(th);
                    const float o0 = av[0] * c - av[1] * sn;
                    const float o1 = av[1] * c + av[0] * sn;
                    av[0] = o0; av[1] = o1;
                }
                bf16_t* dst = O + (bh * S_ + s) * HS_ + lr;
#pragma unroll
                for (int n = 0; n < 4; n++)
                    dst[((4 * wn + n) & 7) * 16] = f2b(av[n]);
            }
        }
    }
}

// ---------------- causal flash attention (r8 structure, best known) ---------
__device__ __forceinline__ void attn_stage(bf16_t* Kd, bf16_t* Vd,
                                           const bf16_t* Kg, const bf16_t* Vg,
                                           int kv0, int wid, int lane) {
#pragma unroll
    for (int jj = 0; jj < 4; jj++) {
        const int c = (wid << 2) + jj;
        const int rk = (c << 2) + (lane >> 4);        // K row 0..63
        async16(Kd + c * 512,
                Kg + (size_t)(kv0 + rk) * HS_ + (((lane & 15) ^ (rk & 7)) << 3));
        const int rv = (c << 3) + (lane >> 3);        // V^T row 0..127
        async16(Vd + c * 512,
                Vg + (size_t)rv * S_ + kv0 + (((lane & 7) ^ (rv & 7)) << 3));
    }
}

__global__ __launch_bounds__(256) void attn_fwd(const bf16_t* __restrict__ Q,
                                                const bf16_t* __restrict__ Kv,
                                                const bf16_t* __restrict__ Vt,
                                                const float* __restrict__ amask,
                                                bf16_t* __restrict__ ctx) {
    __shared__ __align__(16) bf16_t Ks[2][64 * 128];
    __shared__ __align__(16) bf16_t Vs[2][128 * 64];
    __shared__ __align__(16) bf16_t Ps[4][16 * 72];

    const int id = (int)(blockIdx.x + (blockIdx.y << 4));     // 0..511
    const int wg = ((id & 7) << 6) + (id >> 3);               // XCD-bijective
    const int pair = wg & 15;
    const int bh = wg >> 4;
    const int b = bh >> 4, h = bh & 15;
    const int tid = threadIdx.x, wid = tid >> 6, lane = tid & 63;
    const int lr = lane & 15, ls = lane >> 4;
    const float* am = amask + (size_t)b * S_;
    const bf16_t* Kg = Kv + (size_t)bh * S_ * HS_;
    const bf16_t* Vg = Vt + (size_t)bh * HS_ * S_;

#pragma unroll 1
    for (int half = 0; half < 2; ++half) {
        const int qt = half ? pair : (31 - pair);
        const int q0 = qt << 6;
        const int qrow = q0 + wid * 16 + lr;     // this lane's q-row

        bf16x8 qf[4];
        const bf16_t* qp = Q + ((size_t)bh * S_ + qrow) * HS_;
#pragma unroll
        for (int dk = 0; dk < 4; dk++) qf[dk] = *(const bf16x8*)(qp + dk * 32 + ls * 8);

        float mrun = -3.0e38f, lrun = 0.f;
        f32x4 oacc[8];
#pragma unroll
        for (int dt = 0; dt < 8; dt++) oacc[dt] = (f32x4){0.f, 0.f, 0.f, 0.f};

        attn_stage(Ks[0], Vs[0], Kg, Vg, 0, wid, lane);

#pragma unroll 1
        for (int step = 0; step <= qt; ++step) {
            const int cur = step & 1;
            const int kv0 = step << 6;
            if (step < qt) {
                attn_stage(Ks[cur ^ 1], Vs[cur ^ 1], Kg, Vg, (step + 1) << 6, wid, lane);
                WAIT_VM8();
            } else {
                WAIT_VM0();
            }
            BAR();

            // swapped QK^T
            f32x4 sacc[4];
#pragma unroll
            for (int t = 0; t < 4; t++) sacc[t] = (f32x4){0.f, 0.f, 0.f, 0.f};
#pragma unroll
            for (int t = 0; t < 4; t++)
#pragma unroll
                for (int dk = 0; dk < 4; dk++) {
                    const int row = t * 16 + lr;
                    bf16x8 kf = *(const bf16x8*)
                        &Ks[cur][row * 128 + (((dk * 4 + ls) ^ (row & 7)) << 3)];
                    sacc[t] = mfma16(kf, qf[dk], sacc[t]);
                }

            const bool diag = (step == qt);
            float sv[4][4];
            float rmax = -3.0e38f;
#pragma unroll
            for (int t = 0; t < 4; t++) {
                const float4 amv = *(const float4*)&am[kv0 + t * 16 + ls * 4];
                const float amj[4] = { amv.x, amv.y, amv.z, amv.w };
#pragma unroll
                for (int j = 0; j < 4; j++) {
                    const int kvp = kv0 + t * 16 + ls * 4 + j;
                    float v = sacc[t][j] * NORM_ + amj[j];
                    if (diag && kvp > qrow) v = -3.0e38f;
                    sv[t][j] = v;
                    rmax = fmaxf(rmax, v);
                }
            }
            rmax = fmaxf(rmax, __shfl_xor(rmax, 16));
            rmax = fmaxf(rmax, __shfl_xor(rmax, 32));

            if (!__all((int)(rmax <= mrun))) {
                const float mnew = fmaxf(mrun, rmax);
                const float sc = __expf(mrun - mnew);
                lrun *= sc;
                mrun = mnew;
                float scb[4];
#pragma unroll
                for (int j = 0; j < 4; j++) scb[j] = __shfl(sc, ls * 4 + j);
#pragma unroll
                for (int dt = 0; dt < 8; dt++)
#pragma unroll
                    for (int j = 0; j < 4; j++) oacc[dt][j] *= scb[j];
            }

            float psum = 0.f;
#pragma unroll
            for (int t = 0; t < 4; t++) {
                const float p0 = __expf(sv[t][0] - mrun);
                const float p1 = __expf(sv[t][1] - mrun);
                const float p2 = __expf(sv[t][2] - mrun);
                const float p3 = __expf(sv[t][3] - mrun);
                psum += (p0 + p1) + (p2 + p3);
                const unsigned pk0 = (unsigned)f2b(p0) | ((unsigned)f2b(p1) << 16);
                const unsigned pk1 = (unsigned)f2b(p2) | ((unsigned)f2b(p3) << 16);
                *(unsigned*)&Ps[wid][lr * 72 + t * 16 + ls * 4]     = pk0;
                *(unsigned*)&Ps[wid][lr * 72 + t * 16 + ls * 4 + 2] = pk1;
            }
            psum += __shfl_xor(psum, 16);
            psum += __shfl_xor(psum, 32);
            lrun += psum;

            bf16x8 pf[2];
#pragma unroll
            for (int hh = 0; hh < 2; hh++)
                pf[hh] = *(const bf16x8*)&Ps[wid][lr * 72 + hh * 32 + ls * 8];
#pragma unroll
            for (int dt = 0; dt < 8; dt++)
#pragma unroll
                for (int hh = 0; hh < 2; hh++) {
                    const int vrow = dt * 16 + lr;
                    bf16x8 vf = *(const bf16x8*)
                        &Vs[cur][vrow * 64 + (((hh * 4 + ls) ^ (vrow & 7)) << 3)];
                    oacc[dt] = mfma16(pf[hh], vf, oacc[dt]);
                }
            BAR();
        }

        const float inv = 1.0f / lrun;           // q=lr layout
        float invj[4];
#pragma unroll
        for (int j = 0; j < 4; j++) invj[j] = __shfl(inv, ls * 4 + j);
#pragma unroll
        for (int j = 0; j < 4; j++) {
            bf16_t* dst = ctx + ((size_t)b * S_ + q0 + wid * 16 + ls * 4 + j) * H_ + h * HS_;
#pragma unroll
            for (int dt = 0; dt < 8; dt++) dst[dt * 16 + lr] = f2b(oacc[dt][j] * invj[j]);
        }
    }
}

extern "C" void kernel_launch(void* const* d_in, const int* in_sizes, int n_in,
                              void* d_out, int out_size, void* d_ws, size_t ws_size,
                              hipStream_t stream) {
    const float* hs   = (const float*)d_in[0];
    const float* am   = (const float*)d_in[1];
    const int*   pos  = (const int*)d_in[2];
    const float* Wqkv = (const float*)d_in[3];
    const float* bqkv = (const float*)d_in[4];
    const float* Wd   = (const float*)d_in[5];
    const float* bd   = (const float*)d_in[6];
    float* out = (float*)d_out;
    char*  ws  = (char*)d_ws;

    const size_t MB = 1024 * 1024;
    bf16_t* X    = (bf16_t*)(ws);              // 16 MB (reused as ctx)
    bf16_t* WqT  = (bf16_t*)(ws + 16 * MB);    // 24 MB
    bf16_t* WdT  = (bf16_t*)(ws + 40 * MB);    // 8 MB
    bf16_t* Qb   = (bf16_t*)(ws + 48 * MB);    // 16 MB
    bf16_t* Kb   = (bf16_t*)(ws + 64 * MB);    // 16 MB
    bf16_t* Vtb  = (bf16_t*)(ws + 80 * MB);    // 16 MB
    bf16_t* ctx  = X;

    cvt_bf16<<<4096, 256, 0, stream>>>(hs, X);
    transpose_cvt<<<dim3(6144 / 64, 2048 / 64), 256, 0, stream>>>(Wqkv, WqT, 2048, 6144);
    transpose_cvt<<<dim3(2048 / 64, 2048 / 64), 256, 0, stream>>>(Wd, WdT, 2048, 2048);
    gemm_qkv_fused<<<dim3(24, 16), 512, 0, stream>>>(X, WqT, bqkv, pos,
                                                     Qb, Kb, Vtb, 4096, 6144, 2048);
    attn_fwd<<<dim3(16, 32), 256, 0, stream>>>(Qb, Kb, Vtb, am, ctx);
    gemm_bias<0><<<dim3(16, 32), 256, 0, stream>>>(ctx, WdT, bd, out, 4096, 2048, 2048);
}

// Round 16
// 271.806 us; speedup vs baseline: 1.4194x; 1.0819x over previous
//
#include <hip/hip_runtime.h>

#define B_   2
#define S_   2048
#define H_   2048
#define NH_  16
#define HS_  128
#define NORM_ 0.08838834764831845f          // 128^-0.5
#define L2B16 0.8304820237218407f           // log2(10000)/16

typedef unsigned short bf16_t;
typedef __bf16 bf16x8 __attribute__((ext_vector_type(8)));
typedef float  f32x4  __attribute__((ext_vector_type(4)));

__device__ __forceinline__ float b2f(bf16_t u) {
    return __uint_as_float(((unsigned int)u) << 16);
}
__device__ __forceinline__ bf16_t f2b(float f) {
    unsigned int x = __float_as_uint(f);
    x += 0x7fffu + ((x >> 16) & 1u);        // round-to-nearest-even
    return (bf16_t)(x >> 16);
}

__device__ __forceinline__ void async16(bf16_t* lds, const bf16_t* g) {
    __builtin_amdgcn_global_load_lds(
        (const __attribute__((address_space(1))) void*)g,
        (__attribute__((address_space(3))) void*)lds, 16, 0, 0);
}

__device__ __forceinline__ f32x4 mfma16(bf16x8 a, bf16x8 b, f32x4 c) {
    return __builtin_amdgcn_mfma_f32_16x16x32_bf16(a, b, c, 0, 0, 0);
}

#define BAR()        asm volatile("s_barrier" ::: "memory")
#define WAIT_VM0()   asm volatile("s_waitcnt vmcnt(0)" ::: "memory")
#define WAIT_VM8()   asm volatile("s_waitcnt vmcnt(8)" ::: "memory")

// ---------------- f32 -> bf16 convert (8 elems/thread) ----------------
__global__ __launch_bounds__(256) void cvt_bf16(const float* __restrict__ in,
                                                bf16_t* __restrict__ out) {
    const size_t i = (size_t)blockIdx.x * 256 + threadIdx.x;
    const float4* p = (const float4*)in + i * 2;
    float4 a = p[0], b = p[1];
    bf16_t o[8] = { f2b(a.x), f2b(a.y), f2b(a.z), f2b(a.w),
                    f2b(b.x), f2b(b.y), f2b(b.z), f2b(b.w) };
    *((bf16x8*)out + i) = *(const bf16x8*)o;
}

// ---------------- W (KxN f32) -> W^T (NxK bf16), 64x64 tiles, vectorized ----
__global__ __launch_bounds__(256) void transpose_cvt(const float* __restrict__ W,
                                                     bf16_t* __restrict__ WT,
                                                     int K, int N) {
    __shared__ float t[64][65];
    const int n0 = blockIdx.x * 64, k0 = blockIdx.y * 64;
    const int tid = threadIdx.x;
    const int cx = tid & 15, r0 = tid >> 4;
#pragma unroll
    for (int p = 0; p < 4; p++) {
        const int row = p * 16 + r0;
        const float4 v = *(const float4*)&W[(size_t)(k0 + row) * N + n0 + cx * 4];
        t[row][cx * 4 + 0] = v.x;
        t[row][cx * 4 + 1] = v.y;
        t[row][cx * 4 + 2] = v.z;
        t[row][cx * 4 + 3] = v.w;
    }
    __syncthreads();
    const int n = tid >> 2, k8 = tid & 3;
#pragma unroll
    for (int p = 0; p < 2; p++) {
        const int kk = (k8 + p * 4) * 8;
        bf16_t o[8];
#pragma unroll
        for (int i = 0; i < 8; i++) o[i] = f2b(t[kk + i][n]);
        *(bf16x8*)&WT[(size_t)(n0 + n) * K + k0 + kk] = *(const bf16x8*)o;
    }
}

// ---------------- 128x128 2-phase GEMM (dense), XCD 8x8-tiled --------------
template <int BF16OUT>
__global__ __launch_bounds__(256) void gemm_bias(const bf16_t* __restrict__ A,
                                                 const bf16_t* __restrict__ BT,
                                                 const float* __restrict__ bias,
                                                 void* __restrict__ Cv,
                                                 int M, int N, int K) {
    __shared__ __align__(16) bf16_t As[128 * 32];
    __shared__ __align__(16) bf16_t Bs[128 * 32];
    const int id  = (int)(blockIdx.y * gridDim.x + blockIdx.x);
    const int xcd = id & 7, j = id >> 3;
    const int bx  = (xcd & 1) * 8 + (j & 7);       // 0..15
    const int by  = (xcd >> 1) * 8 + (j >> 3);     // 0..31
    const int tid = threadIdx.x;
    const int wid = tid >> 6, lane = tid & 63;
    const int lr = lane & 15, ls = lane >> 4;
    const int wr = wid >> 1, wc = wid & 1;
    const size_t m0 = (size_t)by * 128, n0 = (size_t)bx * 128;

    f32x4 acc[4][4];
#pragma unroll
    for (int m = 0; m < 4; m++)
#pragma unroll
        for (int n = 0; n < 4; n++) acc[m][n] = (f32x4){0.f, 0.f, 0.f, 0.f};

    const int srow = lane >> 2, sk = (lane & 3) * 8;

    for (int k0 = 0; k0 < K; k0 += 32) {
        __syncthreads();
#pragma unroll
        for (int jj = 0; jj < 2; jj++) {
            const int rr = (wid * 2 + jj) * 16 + srow;
            async16(As + (wid * 2 + jj) * 512, A + (m0 + rr) * K + k0 + sk);
            async16(Bs + (wid * 2 + jj) * 512, BT + (n0 + rr) * K + k0 + sk);
        }
        __syncthreads();
        bf16x8 af[4], bfr[4];
#pragma unroll
        for (int m = 0; m < 4; m++)
            af[m] = *(const bf16x8*)&As[(wr * 64 + m * 16 + lr) * 32 + ls * 8];
#pragma unroll
        for (int n = 0; n < 4; n++)
            bfr[n] = *(const bf16x8*)&Bs[(wc * 64 + n * 16 + lr) * 32 + ls * 8];
#pragma unroll
        for (int m = 0; m < 4; m++)
#pragma unroll
            for (int n = 0; n < 4; n++)
                acc[m][n] = mfma16(af[m], bfr[n], acc[m][n]);
    }

    float bv[4];
#pragma unroll
    for (int n = 0; n < 4; n++) bv[n] = bias[n0 + wc * 64 + n * 16 + lr];
#pragma unroll
    for (int m = 0; m < 4; m++)
#pragma unroll
        for (int n = 0; n < 4; n++)
#pragma unroll
            for (int jj = 0; jj < 4; jj++) {
                const size_t row = m0 + wr * 64 + m * 16 + ls * 4 + jj;
                const size_t col = n0 + wc * 64 + n * 16 + lr;
                const float v = acc[m][n][jj] + bv[n];
                if (BF16OUT) ((bf16_t*)Cv)[row * N + col] = f2b(v);
                else         ((float*)Cv)[row * N + col] = v;
            }
}

// ---------------- shared staging helper (512-thread blocks) ----------------
__device__ __forceinline__ void st512(bf16_t* lds, const bf16_t* g,
                                      int K, int part, int tid) {
    const int idx = part * 512 + tid;
    const int row = idx >> 3, slot = idx & 7;
    async16(lds + idx * 8, g + (size_t)row * K + ((slot ^ (row & 7)) << 3));
}

#define LDAQ(dst, ab, q) do {                                                  \
    _Pragma("unroll")                                                          \
    for (int m = 0; m < 2; m++)                                                \
        _Pragma("unroll")                                                      \
        for (int ks = 0; ks < 2; ks++) {                                       \
            const int r = wm * 128 + (q) * 32 + m * 16 + lr;                   \
            dst[m][ks] = *(const bf16x8*)                                      \
                &(ab)[r * 64 + (((ks * 4 + ls) ^ (r & 7)) << 3)];              \
        }                                                                      \
} while (0)

#define LDB3(bb) do {                                                          \
    _Pragma("unroll")                                                          \
    for (int n = 0; n < 3; n++)                                                \
        _Pragma("unroll")                                                      \
        for (int ks = 0; ks < 2; ks++) {                                       \
            const int r = wn * 48 + n * 16 + lr;                               \
            bfr[n][ks] = *(const bf16x8*)                                      \
                &(bb)[r * 64 + (((ks * 4 + ls) ^ (r & 7)) << 3)];              \
        }                                                                      \
} while (0)

#define MMA3(q, src) do {                                                      \
    __builtin_amdgcn_s_setprio(1);                                             \
    _Pragma("unroll")                                                          \
    for (int ks = 0; ks < 2; ks++)                                             \
        _Pragma("unroll")                                                      \
        for (int n = 0; n < 3; n++)                                            \
            _Pragma("unroll")                                                  \
            for (int m = 0; m < 2; m++)                                        \
                acc[(q) * 2 + m][n] =                                          \
                    mfma16(src[m][ks], bfr[n][ks], acc[(q) * 2 + m][n]);       \
    __builtin_amdgcn_s_setprio(0);                                             \
} while (0)

// ---------------- fused QKV GEMM: 256x192 (proven loop) + RoPE epilogue -----
// grid (32,16)=512 blocks = 2 exact rounds; main loop identical to r13's
// 120us kernel. BN=192 slice decode (nh = bx>>1 always):
//   even bx: off<128 -> Q d0=off        ; off>=128 -> K d0=off-128 (d0<64)
//   odd  bx: off<64  -> K d0=off+64     ; off>=64  -> V d0=off-64
// RoPE pairs in-thread (wn0: n0<->n1) except K d0=0<->16 on even bx:
// wn=2 frag n=2 <-> wn=3 frag n=0 (same wm) -> 32KB LDS exchange (reuse As).
__global__ __launch_bounds__(512, 2) void gemm_qkv_fused(
        const bf16_t* __restrict__ A, const bf16_t* __restrict__ BT,
        const float* __restrict__ bias, const int* __restrict__ pos_ids,
        bf16_t* __restrict__ Qo, bf16_t* __restrict__ Ko,
        bf16_t* __restrict__ Vt, int M, int N, int K) {
    __shared__ __align__(16) bf16_t As[2][256 * 64];
    __shared__ __align__(16) bf16_t Bs[2][192 * 64];

    const int id  = (int)(blockIdx.y * gridDim.x + blockIdx.x);
    const int xcd = id & 7, j0 = id >> 3;
    const int bx  = (xcd & 3) * 8 + (j0 & 7);      // 0..31
    const int by  = (xcd >> 2) * 8 + (j0 >> 3);    // 0..15

    const int tid = threadIdx.x;
    const int wid = tid >> 6, lane = tid & 63;
    const int lr = lane & 15, ls = lane >> 4;
    const int wm = wid >> 2, wn = wid & 3;
    const size_t m0 = (size_t)by * 256, n0 = (size_t)bx * 192;

    const bf16_t* Ab = A + m0 * K;
    const bf16_t* Bb = BT + n0 * K;

    f32x4 acc[8][3];
#pragma unroll
    for (int m = 0; m < 8; m++)
#pragma unroll
        for (int n = 0; n < 3; n++) acc[m][n] = (f32x4){0.f, 0.f, 0.f, 0.f};
    bf16x8 bfr[3][2];
    bf16x8 afP[2][2], afQ[2][2];

#pragma unroll
    for (int p = 0; p < 4; p++) st512(As[0], Ab, K, p, tid);
#pragma unroll
    for (int p = 0; p < 3; p++) st512(Bs[0], Bb, K, p, tid);
    WAIT_VM0();
    BAR();

    const int nt = K >> 6;
#pragma unroll 1
    for (int i = 0; i < nt; ++i) {
        const int c = i & 1;
        const bf16_t* Ac = As[c];
        const bf16_t* Bc = Bs[c];
        if (i + 1 < nt) {
            const size_t ko = (size_t)(i + 1) * 64;
            bf16_t* Ad = As[c ^ 1];
            bf16_t* Bd = Bs[c ^ 1];
#pragma unroll
            for (int p = 0; p < 4; p++) st512(Ad, Ab + ko, K, p, tid);
#pragma unroll
            for (int p = 0; p < 3; p++) st512(Bd, Bb + ko, K, p, tid);
        }
        __builtin_amdgcn_sched_barrier(0);
        LDAQ(afP, Ac, 0);
        LDB3(Bc);
        LDAQ(afQ, Ac, 1);
        MMA3(0, afP);
        LDAQ(afP, Ac, 2);
        MMA3(1, afQ);
        LDAQ(afQ, Ac, 3);
        MMA3(2, afP);
        MMA3(3, afQ);
        WAIT_VM0();
        BAR();
    }

    // -------- epilogue: bias, RoPE (with one cross-wave exchange), scatter --
    const bool evenbx = ((bx & 1) == 0);
    const int  nh     = bx >> 1;
    {
        float bv[3];
#pragma unroll
        for (int n = 0; n < 3; n++) bv[n] = bias[n0 + wn * 48 + n * 16 + lr];
#pragma unroll
        for (int mm = 0; mm < 8; mm++)
#pragma unroll
            for (int n = 0; n < 3; n++)
#pragma unroll
                for (int j = 0; j < 4; j++) acc[mm][n][j] += bv[n];
    }

    // exchange K(d0=0) <-> K(d0=16) values for even tiles (wn2.n2 <-> wn3.n0)
    float* XB = (float*)&As[0][0];               // safe after final BAR
    if (evenbx && wn == 2) {
#pragma unroll
        for (int mm = 0; mm < 8; mm++)
#pragma unroll
            for (int j = 0; j < 4; j++)
                XB[((((wm * 8 + mm) * 4 + ls) * 4 + j) * 16) + lr] = acc[mm][2][j];
    }
    if (evenbx && wn == 3) {
#pragma unroll
        for (int mm = 0; mm < 8; mm++)
#pragma unroll
            for (int j = 0; j < 4; j++)
                XB[4096 + ((((wm * 8 + mm) * 4 + ls) * 4 + j) * 16) + lr] = acc[mm][0][j];
    }
    __syncthreads();

    const float invf = __builtin_exp2f(-(float)lr * L2B16);

    if (evenbx && wn == 0) {                     // Q rot: n=0 (d=lr), n=1 (d=16+lr)
#pragma unroll
        for (int mm = 0; mm < 8; mm++) {
            const int row0 = (int)m0 + wm * 128 + mm * 16 + ls * 4;
#pragma unroll
            for (int j = 0; j < 4; j++) {
                const float th = (float)pos_ids[row0 + j] * invf;
                const float c = __cosf(th), sn = __sinf(th);
                const float x = acc[mm][0][j], y = acc[mm][1][j];
                acc[mm][0][j] = x * c - y * sn;
                acc[mm][1][j] = y * c + x * sn;
            }
        }
    }
    if (evenbx && wn == 2) {                     // K low rot: n=2 (d=lr)
#pragma unroll
        for (int mm = 0; mm < 8; mm++) {
            const int row0 = (int)m0 + wm * 128 + mm * 16 + ls * 4;
#pragma unroll
            for (int j = 0; j < 4; j++) {
                const float th = (float)pos_ids[row0 + j] * invf;
                const float c = __cosf(th), sn = __sinf(th);
                const float y = XB[4096 + ((((wm * 8 + mm) * 4 + ls) * 4 + j) * 16) + lr];
                acc[mm][2][j] = acc[mm][2][j] * c - y * sn;
            }
        }
    }
    if (evenbx && wn == 3) {                     // K high rot: n=0 (d=16+lr)
#pragma unroll
        for (int mm = 0; mm < 8; mm++) {
            const int row0 = (int)m0 + wm * 128 + mm * 16 + ls * 4;
#pragma unroll
            for (int j = 0; j < 4; j++) {
                const float th = (float)pos_ids[row0 + j] * invf;
                const float c = __cosf(th), sn = __sinf(th);
                const float y = XB[((((wm * 8 + mm) * 4 + ls) * 4 + j) * 16) + lr];
                acc[mm][0][j] = acc[mm][0][j] * c + y * sn;
            }
        }
    }

    // stores
#pragma unroll
    for (int n = 0; n < 3; n++) {
        const int off = wn * 48 + n * 16;
        int which, d0;
        if (evenbx) { which = (off < 128) ? 0 : 1; d0 = (off < 128) ? off : off - 128; }
        else        { which = (off < 64) ? 1 : 2;  d0 = (off < 64) ? off + 64 : off - 64; }
#pragma unroll
        for (int mm = 0; mm < 8; mm++) {
            const int row0 = (int)m0 + wm * 128 + mm * 16 + ls * 4;
            const int b = row0 >> 11, s0 = row0 & 2047;
            const size_t bh = (size_t)(b * NH_ + nh);
            if (which == 2) {                    // V -> V^T[bh][d][s]
                bf16_t o[4];
#pragma unroll
                for (int j = 0; j < 4; j++) o[j] = f2b(acc[mm][n][j]);
                *(uint2*)&Vt[(bh * HS_ + d0 + lr) * S_ + s0] = *(const uint2*)o;
            } else {
                bf16_t* O = which ? Ko : Qo;
#pragma unroll
                for (int j = 0; j < 4; j++)
                    O[(bh * S_ + s0 + j) * HS_ + d0 + lr] = f2b(acc[mm][n][j]);
            }
        }
    }
}

// ---------------- causal flash attention (r8 structure, best known) ---------
__device__ __forceinline__ void attn_stage(bf16_t* Kd, bf16_t* Vd,
                                           const bf16_t* Kg, const bf16_t* Vg,
                                           int kv0, int wid, int lane) {
#pragma unroll
    for (int jj = 0; jj < 4; jj++) {
        const int c = (wid << 2) + jj;
        const int rk = (c << 2) + (lane >> 4);        // K row 0..63
        async16(Kd + c * 512,
                Kg + (size_t)(kv0 + rk) * HS_ + (((lane & 15) ^ (rk & 7)) << 3));
        const int rv = (c << 3) + (lane >> 3);        // V^T row 0..127
        async16(Vd + c * 512,
                Vg + (size_t)rv * S_ + kv0 + (((lane & 7) ^ (rv & 7)) << 3));
    }
}

__global__ __launch_bounds__(256) void attn_fwd(const bf16_t* __restrict__ Q,
                                                const bf16_t* __restrict__ Kv,
                                                const bf16_t* __restrict__ Vt,
                                                const float* __restrict__ amask,
                                                bf16_t* __restrict__ ctx) {
    __shared__ __align__(16) bf16_t Ks[2][64 * 128];
    __shared__ __align__(16) bf16_t Vs[2][128 * 64];
    __shared__ __align__(16) bf16_t Ps[4][16 * 72];

    const int id = (int)(blockIdx.x + (blockIdx.y << 4));     // 0..511
    const int wg = ((id & 7) << 6) + (id >> 3);               // XCD-bijective
    const int pair = wg & 15;
    const int bh = wg >> 4;
    const int b = bh >> 4, h = bh & 15;
    const int tid = threadIdx.x, wid = tid >> 6, lane = tid & 63;
    const int lr = lane & 15, ls = lane >> 4;
    const float* am = amask + (size_t)b * S_;
    const bf16_t* Kg = Kv + (size_t)bh * S_ * HS_;
    const bf16_t* Vg = Vt + (size_t)bh * HS_ * S_;

#pragma unroll 1
    for (int half = 0; half < 2; ++half) {
        const int qt = half ? pair : (31 - pair);
        const int q0 = qt << 6;
        const int qrow = q0 + wid * 16 + lr;     // this lane's q-row

        bf16x8 qf[4];
        const bf16_t* qp = Q + ((size_t)bh * S_ + qrow) * HS_;
#pragma unroll
        for (int dk = 0; dk < 4; dk++) qf[dk] = *(const bf16x8*)(qp + dk * 32 + ls * 8);

        float mrun = -3.0e38f, lrun = 0.f;
        f32x4 oacc[8];
#pragma unroll
        for (int dt = 0; dt < 8; dt++) oacc[dt] = (f32x4){0.f, 0.f, 0.f, 0.f};

        attn_stage(Ks[0], Vs[0], Kg, Vg, 0, wid, lane);

#pragma unroll 1
        for (int step = 0; step <= qt; ++step) {
            const int cur = step & 1;
            const int kv0 = step << 6;
            if (step < qt) {
                attn_stage(Ks[cur ^ 1], Vs[cur ^ 1], Kg, Vg, (step + 1) << 6, wid, lane);
                WAIT_VM8();
            } else {
                WAIT_VM0();
            }
            BAR();

            // swapped QK^T
            f32x4 sacc[4];
#pragma unroll
            for (int t = 0; t < 4; t++) sacc[t] = (f32x4){0.f, 0.f, 0.f, 0.f};
#pragma unroll
            for (int t = 0; t < 4; t++)
#pragma unroll
                for (int dk = 0; dk < 4; dk++) {
                    const int row = t * 16 + lr;
                    bf16x8 kf = *(const bf16x8*)
                        &Ks[cur][row * 128 + (((dk * 4 + ls) ^ (row & 7)) << 3)];
                    sacc[t] = mfma16(kf, qf[dk], sacc[t]);
                }

            const bool diag = (step == qt);
            float sv[4][4];
            float rmax = -3.0e38f;
#pragma unroll
            for (int t = 0; t < 4; t++) {
                const float4 amv = *(const float4*)&am[kv0 + t * 16 + ls * 4];
                const float amj[4] = { amv.x, amv.y, amv.z, amv.w };
#pragma unroll
                for (int j = 0; j < 4; j++) {
                    const int kvp = kv0 + t * 16 + ls * 4 + j;
                    float v = sacc[t][j] * NORM_ + amj[j];
                    if (diag && kvp > qrow) v = -3.0e38f;
                    sv[t][j] = v;
                    rmax = fmaxf(rmax, v);
                }
            }
            rmax = fmaxf(rmax, __shfl_xor(rmax, 16));
            rmax = fmaxf(rmax, __shfl_xor(rmax, 32));

            if (!__all((int)(rmax <= mrun))) {
                const float mnew = fmaxf(mrun, rmax);
                const float sc = __expf(mrun - mnew);
                lrun *= sc;
                mrun = mnew;
                float scb[4];
#pragma unroll
                for (int j = 0; j < 4; j++) scb[j] = __shfl(sc, ls * 4 + j);
#pragma unroll
                for (int dt = 0; dt < 8; dt++)
#pragma unroll
                    for (int j = 0; j < 4; j++) oacc[dt][j] *= scb[j];
            }

            float psum = 0.f;
#pragma unroll
            for (int t = 0; t < 4; t++) {
                const float p0 = __expf(sv[t][0] - mrun);
                const float p1 = __expf(sv[t][1] - mrun);
                const float p2 = __expf(sv[t][2] - mrun);
                const float p3 = __expf(sv[t][3] - mrun);
                psum += (p0 + p1) + (p2 + p3);
                const unsigned pk0 = (unsigned)f2b(p0) | ((unsigned)f2b(p1) << 16);
                const unsigned pk1 = (unsigned)f2b(p2) | ((unsigned)f2b(p3) << 16);
                *(unsigned*)&Ps[wid][lr * 72 + t * 16 + ls * 4]     = pk0;
                *(unsigned*)&Ps[wid][lr * 72 + t * 16 + ls * 4 + 2] = pk1;
            }
            psum += __shfl_xor(psum, 16);
            psum += __shfl_xor(psum, 32);
            lrun += psum;

            bf16x8 pf[2];
#pragma unroll
            for (int hh = 0; hh < 2; hh++)
                pf[hh] = *(const bf16x8*)&Ps[wid][lr * 72 + hh * 32 + ls * 8];
#pragma unroll
            for (int dt = 0; dt < 8; dt++)
#pragma unroll
                for (int hh = 0; hh < 2; hh++) {
                    const int vrow = dt * 16 + lr;
                    bf16x8 vf = *(const bf16x8*)
                        &Vs[cur][vrow * 64 + (((hh * 4 + ls) ^ (vrow & 7)) << 3)];
                    oacc[dt] = mfma16(pf[hh], vf, oacc[dt]);
                }
            BAR();
        }

        const float inv = 1.0f / lrun;           // q=lr layout
        float invj[4];
#pragma unroll
        for (int j = 0; j < 4; j++) invj[j] = __shfl(inv, ls * 4 + j);
#pragma unroll
        for (int j = 0; j < 4; j++) {
            bf16_t* dst = ctx + ((size_t)b * S_ + q0 + wid * 16 + ls * 4 + j) * H_ + h * HS_;
#pragma unroll
            for (int dt = 0; dt < 8; dt++) dst[dt * 16 + lr] = f2b(oacc[dt][j] * invj[j]);
        }
    }
}

extern "C" void kernel_launch(void* const* d_in, const int* in_sizes, int n_in,
                              void* d_out, int out_size, void* d_ws, size_t ws_size,
                              hipStream_t stream) {
    const float* hs   = (const float*)d_in[0];
    const float* am   = (const float*)d_in[1];
    const int*   pos  = (const int*)d_in[2];
    const float* Wqkv = (const float*)d_in[3];
    const float* bqkv = (const float*)d_in[4];
    const float* Wd   = (const float*)d_in[5];
    const float* bd   = (const float*)d_in[6];
    float* out = (float*)d_out;
    char*  ws  = (char*)d_ws;

    const size_t MB = 1024 * 1024;
    bf16_t* X    = (bf16_t*)(ws);              // 16 MB (reused as ctx)
    bf16_t* WqT  = (bf16_t*)(ws + 16 * MB);    // 24 MB
    bf16_t* WdT  = (bf16_t*)(ws + 40 * MB);    // 8 MB
    bf16_t* Qb   = (bf16_t*)(ws + 48 * MB);    // 16 MB
    bf16_t* Kb   = (bf16_t*)(ws + 64 * MB);    // 16 MB
    bf16_t* Vtb  = (bf16_t*)(ws + 80 * MB);    // 16 MB
    bf16_t* ctx  = X;

    cvt_bf16<<<4096, 256, 0, stream>>>(hs, X);
    transpose_cvt<<<dim3(6144 / 64, 2048 / 64), 256, 0, stream>>>(Wqkv, WqT, 2048, 6144);
    transpose_cvt<<<dim3(2048 / 64, 2048 / 64), 256, 0, stream>>>(Wd, WdT, 2048, 2048);
    gemm_qkv_fused<<<dim3(32, 16), 512, 0, stream>>>(X, WqT, bqkv, pos,
                                                     Qb, Kb, Vtb, 4096, 6144, 2048);
    attn_fwd<<<dim3(16, 32), 256, 0, stream>>>(Qb, Kb, Vtb, am, ctx);
    gemm_bias<0><<<dim3(16, 32), 256, 0, stream>>>(ctx, WdT, bd, out, 4096, 2048, 2048);
}

// Round 17
// 270.038 us; speedup vs baseline: 1.4287x; 1.0065x over previous
//
#include <hip/hip_runtime.h>

#define B_   2
#define S_   2048
#define H_   2048
#define NH_  16
#define HS_  128
#define NORM_ 0.08838834764831845f          // 128^-0.5
#define L2B16 0.8304820237218407f           // log2(10000)/16

typedef unsigned short bf16_t;
typedef __bf16 bf16x8 __attribute__((ext_vector_type(8)));
typedef float  f32x4  __attribute__((ext_vector_type(4)));

__device__ __forceinline__ float b2f(bf16_t u) {
    return __uint_as_float(((unsigned int)u) << 16);
}
__device__ __forceinline__ bf16_t f2b(float f) {
    unsigned int x = __float_as_uint(f);
    x += 0x7fffu + ((x >> 16) & 1u);        // round-to-nearest-even
    return (bf16_t)(x >> 16);
}

__device__ __forceinline__ void async16(bf16_t* lds, const bf16_t* g) {
    __builtin_amdgcn_global_load_lds(
        (const __attribute__((address_space(1))) void*)g,
        (__attribute__((address_space(3))) void*)lds, 16, 0, 0);
}

__device__ __forceinline__ f32x4 mfma16(bf16x8 a, bf16x8 b, f32x4 c) {
    return __builtin_amdgcn_mfma_f32_16x16x32_bf16(a, b, c, 0, 0, 0);
}

#define BAR()        asm volatile("s_barrier" ::: "memory")
#define WAIT_VM0()   asm volatile("s_waitcnt vmcnt(0)" ::: "memory")
#define WAIT_VM8()   asm volatile("s_waitcnt vmcnt(8)" ::: "memory")

// ---------------- f32 -> bf16 convert (8 elems/thread) ----------------
__global__ __launch_bounds__(256) void cvt_bf16(const float* __restrict__ in,
                                                bf16_t* __restrict__ out) {
    const size_t i = (size_t)blockIdx.x * 256 + threadIdx.x;
    const float4* p = (const float4*)in + i * 2;
    float4 a = p[0], b = p[1];
    bf16_t o[8] = { f2b(a.x), f2b(a.y), f2b(a.z), f2b(a.w),
                    f2b(b.x), f2b(b.y), f2b(b.z), f2b(b.w) };
    *((bf16x8*)out + i) = *(const bf16x8*)o;
}

// ---------------- W (KxN f32) -> W^T (NxK bf16), 64x64 tiles, vectorized ----
__global__ __launch_bounds__(256) void transpose_cvt(const float* __restrict__ W,
                                                     bf16_t* __restrict__ WT,
                                                     int K, int N) {
    __shared__ float t[64][65];
    const int n0 = blockIdx.x * 64, k0 = blockIdx.y * 64;
    const int tid = threadIdx.x;
    const int cx = tid & 15, r0 = tid >> 4;
#pragma unroll
    for (int p = 0; p < 4; p++) {
        const int row = p * 16 + r0;
        const float4 v = *(const float4*)&W[(size_t)(k0 + row) * N + n0 + cx * 4];
        t[row][cx * 4 + 0] = v.x;
        t[row][cx * 4 + 1] = v.y;
        t[row][cx * 4 + 2] = v.z;
        t[row][cx * 4 + 3] = v.w;
    }
    __syncthreads();
    const int n = tid >> 2, k8 = tid & 3;
#pragma unroll
    for (int p = 0; p < 2; p++) {
        const int kk = (k8 + p * 4) * 8;
        bf16_t o[8];
#pragma unroll
        for (int i = 0; i < 8; i++) o[i] = f2b(t[kk + i][n]);
        *(bf16x8*)&WT[(size_t)(n0 + n) * K + k0 + kk] = *(const bf16x8*)o;
    }
}

// ---------------- 128x128 2-phase GEMM (dense), XCD 8x8-tiled --------------
template <int BF16OUT>
__global__ __launch_bounds__(256) void gemm_bias(const bf16_t* __restrict__ A,
                                                 const bf16_t* __restrict__ BT,
                                                 const float* __restrict__ bias,
                                                 void* __restrict__ Cv,
                                                 int M, int N, int K) {
    __shared__ __align__(16) bf16_t As[128 * 32];
    __shared__ __align__(16) bf16_t Bs[128 * 32];
    const int id  = (int)(blockIdx.y * gridDim.x + blockIdx.x);
    const int xcd = id & 7, j = id >> 3;
    const int bx  = (xcd & 1) * 8 + (j & 7);       // 0..15
    const int by  = (xcd >> 1) * 8 + (j >> 3);     // 0..31
    const int tid = threadIdx.x;
    const int wid = tid >> 6, lane = tid & 63;
    const int lr = lane & 15, ls = lane >> 4;
    const int wr = wid >> 1, wc = wid & 1;
    const size_t m0 = (size_t)by * 128, n0 = (size_t)bx * 128;

    f32x4 acc[4][4];
#pragma unroll
    for (int m = 0; m < 4; m++)
#pragma unroll
        for (int n = 0; n < 4; n++) acc[m][n] = (f32x4){0.f, 0.f, 0.f, 0.f};

    const int srow = lane >> 2, sk = (lane & 3) * 8;

    for (int k0 = 0; k0 < K; k0 += 32) {
        __syncthreads();
#pragma unroll
        for (int jj = 0; jj < 2; jj++) {
            const int rr = (wid * 2 + jj) * 16 + srow;
            async16(As + (wid * 2 + jj) * 512, A + (m0 + rr) * K + k0 + sk);
            async16(Bs + (wid * 2 + jj) * 512, BT + (n0 + rr) * K + k0 + sk);
        }
        __syncthreads();
        bf16x8 af[4], bfr[4];
#pragma unroll
        for (int m = 0; m < 4; m++)
            af[m] = *(const bf16x8*)&As[(wr * 64 + m * 16 + lr) * 32 + ls * 8];
#pragma unroll
        for (int n = 0; n < 4; n++)
            bfr[n] = *(const bf16x8*)&Bs[(wc * 64 + n * 16 + lr) * 32 + ls * 8];
#pragma unroll
        for (int m = 0; m < 4; m++)
#pragma unroll
            for (int n = 0; n < 4; n++)
                acc[m][n] = mfma16(af[m], bfr[n], acc[m][n]);
    }

    float bv[4];
#pragma unroll
    for (int n = 0; n < 4; n++) bv[n] = bias[n0 + wc * 64 + n * 16 + lr];
#pragma unroll
    for (int m = 0; m < 4; m++)
#pragma unroll
        for (int n = 0; n < 4; n++)
#pragma unroll
            for (int jj = 0; jj < 4; jj++) {
                const size_t row = m0 + wr * 64 + m * 16 + ls * 4 + jj;
                const size_t col = n0 + wc * 64 + n * 16 + lr;
                const float v = acc[m][n][jj] + bv[n];
                if (BF16OUT) ((bf16_t*)Cv)[row * N + col] = f2b(v);
                else         ((float*)Cv)[row * N + col] = v;
            }
}

// ---------------- shared staging helper (512-thread blocks) ----------------
__device__ __forceinline__ void st512(bf16_t* lds, const bf16_t* g,
                                      int K, int part, int tid) {
    const int idx = part * 512 + tid;
    const int row = idx >> 3, slot = idx & 7;
    async16(lds + idx * 8, g + (size_t)row * K + ((slot ^ (row & 7)) << 3));
}

// A-frag load for BM=128 (per-wave 64 rows): q in {0,1}
#define LDAQ2(dst, ab, q) do {                                                 \
    _Pragma("unroll")                                                          \
    for (int m = 0; m < 2; m++)                                                \
        _Pragma("unroll")                                                      \
        for (int ks = 0; ks < 2; ks++) {                                       \
            const int r = wm * 64 + (q) * 32 + m * 16 + lr;                    \
            dst[m][ks] = *(const bf16x8*)                                      \
                &(ab)[r * 64 + (((ks * 4 + ls) ^ (r & 7)) << 3)];              \
        }                                                                      \
} while (0)

#define LDB3(bb) do {                                                          \
    _Pragma("unroll")                                                          \
    for (int n = 0; n < 3; n++)                                                \
        _Pragma("unroll")                                                      \
        for (int ks = 0; ks < 2; ks++) {                                       \
            const int r = wn * 48 + n * 16 + lr;                               \
            bfr[n][ks] = *(const bf16x8*)                                      \
                &(bb)[r * 64 + (((ks * 4 + ls) ^ (r & 7)) << 3)];              \
        }                                                                      \
} while (0)

#define MMA3(q, src) do {                                                      \
    __builtin_amdgcn_s_setprio(1);                                             \
    _Pragma("unroll")                                                          \
    for (int ks = 0; ks < 2; ks++)                                             \
        _Pragma("unroll")                                                      \
        for (int n = 0; n < 3; n++)                                            \
            _Pragma("unroll")                                                  \
            for (int m = 0; m < 2; m++)                                        \
                acc[(q) * 2 + m][n] =                                          \
                    mfma16(src[m][ks], bfr[n][ks], acc[(q) * 2 + m][n]);       \
    __builtin_amdgcn_s_setprio(0);                                             \
} while (0)

// ---------------- fused QKV GEMM: 128x192, 80KB LDS (2 blocks/CU) -----------
// grid (32,32) = 1024 = 2 rounds x 2 blocks/CU. Cross-block implicit overlap
// (m114) fills the per-tile vmcnt(0)+barrier stall that 1-block residency
// could not. Same slice decode + RoPE epilogue as r16 (nh=bx>>1; even bx:
// Q full + K lo, odd bx: K hi + V). K d0=0<->16 pair exchanged via 16KB of
// dead As LDS between wn=2(frag n2) and wn=3(frag n0).
__global__ __launch_bounds__(512, 2) void gemm_qkv_fused(
        const bf16_t* __restrict__ A, const bf16_t* __restrict__ BT,
        const float* __restrict__ bias, const int* __restrict__ pos_ids,
        bf16_t* __restrict__ Qo, bf16_t* __restrict__ Ko,
        bf16_t* __restrict__ Vt, int M, int N, int K) {
    __shared__ __align__(16) bf16_t As[2][128 * 64];
    __shared__ __align__(16) bf16_t Bs[2][192 * 64];

    const int id  = (int)(blockIdx.y * gridDim.x + blockIdx.x);   // 0..1023
    const int xcd = id & 7, j0 = id >> 3;                         // j0 0..127
    const int bx  = (xcd & 3) * 8 + (j0 & 7);      // 0..31
    const int by  = (xcd >> 2) * 16 + (j0 >> 3);   // 0..31

    const int tid = threadIdx.x;
    const int wid = tid >> 6, lane = tid & 63;
    const int lr = lane & 15, ls = lane >> 4;
    const int wm = wid >> 2, wn = wid & 3;
    const size_t m0 = (size_t)by * 128, n0 = (size_t)bx * 192;

    const bf16_t* Ab = A + m0 * K;
    const bf16_t* Bb = BT + n0 * K;

    f32x4 acc[4][3];
#pragma unroll
    for (int m = 0; m < 4; m++)
#pragma unroll
        for (int n = 0; n < 3; n++) acc[m][n] = (f32x4){0.f, 0.f, 0.f, 0.f};
    bf16x8 bfr[3][2];
    bf16x8 afP[2][2], afQ[2][2];

#pragma unroll
    for (int p = 0; p < 2; p++) st512(As[0], Ab, K, p, tid);
#pragma unroll
    for (int p = 0; p < 3; p++) st512(Bs[0], Bb, K, p, tid);
    WAIT_VM0();
    BAR();

    const int nt = K >> 6;
#pragma unroll 1
    for (int i = 0; i < nt; ++i) {
        const int c = i & 1;
        const bf16_t* Ac = As[c];
        const bf16_t* Bc = Bs[c];
        if (i + 1 < nt) {
            const size_t ko = (size_t)(i + 1) * 64;
            bf16_t* Ad = As[c ^ 1];
            bf16_t* Bd = Bs[c ^ 1];
#pragma unroll
            for (int p = 0; p < 2; p++) st512(Ad, Ab + ko, K, p, tid);
#pragma unroll
            for (int p = 0; p < 3; p++) st512(Bd, Bb + ko, K, p, tid);
        }
        __builtin_amdgcn_sched_barrier(0);
        LDAQ2(afP, Ac, 0);
        LDB3(Bc);
        LDAQ2(afQ, Ac, 1);
        MMA3(0, afP);
        MMA3(1, afQ);
        WAIT_VM0();
        BAR();
    }

    // -------- epilogue: bias, RoPE (one cross-wave exchange), scatter --------
    const bool evenbx = ((bx & 1) == 0);
    const int  nh     = bx >> 1;
    {
        float bv[3];
#pragma unroll
        for (int n = 0; n < 3; n++) bv[n] = bias[n0 + wn * 48 + n * 16 + lr];
#pragma unroll
        for (int mm = 0; mm < 4; mm++)
#pragma unroll
            for (int n = 0; n < 3; n++)
#pragma unroll
                for (int j = 0; j < 4; j++) acc[mm][n][j] += bv[n];
    }

    // exchange K(d0=0) <-> K(d0=16) for even tiles (wn2.n2 <-> wn3.n0)
    float* XB = (float*)&As[0][0];               // dead after final BAR
    if (evenbx && wn == 2) {
#pragma unroll
        for (int mm = 0; mm < 4; mm++)
#pragma unroll
            for (int j = 0; j < 4; j++)
                XB[((((wm * 4 + mm) * 4 + ls) * 4 + j) * 16) + lr] = acc[mm][2][j];
    }
    if (evenbx && wn == 3) {
#pragma unroll
        for (int mm = 0; mm < 4; mm++)
#pragma unroll
            for (int j = 0; j < 4; j++)
                XB[2048 + ((((wm * 4 + mm) * 4 + ls) * 4 + j) * 16) + lr] = acc[mm][0][j];
    }
    __syncthreads();

    const float invf = __builtin_exp2f(-(float)lr * L2B16);

    if (evenbx && wn == 0) {                     // Q rot: n=0 (d=lr), n=1 (d=16+lr)
#pragma unroll
        for (int mm = 0; mm < 4; mm++) {
            const int row0 = (int)m0 + wm * 64 + mm * 16 + ls * 4;
#pragma unroll
            for (int j = 0; j < 4; j++) {
                const float th = (float)pos_ids[row0 + j] * invf;
                const float c = __cosf(th), sn = __sinf(th);
                const float x = acc[mm][0][j], y = acc[mm][1][j];
                acc[mm][0][j] = x * c - y * sn;
                acc[mm][1][j] = y * c + x * sn;
            }
        }
    }
    if (evenbx && wn == 2) {                     // K low rot: n=2 (d=lr)
#pragma unroll
        for (int mm = 0; mm < 4; mm++) {
            const int row0 = (int)m0 + wm * 64 + mm * 16 + ls * 4;
#pragma unroll
            for (int j = 0; j < 4; j++) {
                const float th = (float)pos_ids[row0 + j] * invf;
                const float c = __cosf(th), sn = __sinf(th);
                const float y = XB[2048 + ((((wm * 4 + mm) * 4 + ls) * 4 + j) * 16) + lr];
                acc[mm][2][j] = acc[mm][2][j] * c - y * sn;
            }
        }
    }
    if (evenbx && wn == 3) {                     // K high rot: n=0 (d=16+lr)
#pragma unroll
        for (int mm = 0; mm < 4; mm++) {
            const int row0 = (int)m0 + wm * 64 + mm * 16 + ls * 4;
#pragma unroll
            for (int j = 0; j < 4; j++) {
                const float th = (float)pos_ids[row0 + j] * invf;
                const float c = __cosf(th), sn = __sinf(th);
                const float y = XB[((((wm * 4 + mm) * 4 + ls) * 4 + j) * 16) + lr];
                acc[mm][0][j] = acc[mm][0][j] * c + y * sn;
            }
        }
    }

    // stores
#pragma unroll
    for (int n = 0; n < 3; n++) {
        const int off = wn * 48 + n * 16;
        int which, d0;
        if (evenbx) { which = (off < 128) ? 0 : 1; d0 = (off < 128) ? off : off - 128; }
        else        { which = (off < 64) ? 1 : 2;  d0 = (off < 64) ? off + 64 : off - 64; }
#pragma unroll
        for (int mm = 0; mm < 4; mm++) {
            const int row0 = (int)m0 + wm * 64 + mm * 16 + ls * 4;
            const int b = row0 >> 11, s0 = row0 & 2047;
            const size_t bh = (size_t)(b * NH_ + nh);
            if (which == 2) {                    // V -> V^T[bh][d][s]
                bf16_t o[4];
#pragma unroll
                for (int j = 0; j < 4; j++) o[j] = f2b(acc[mm][n][j]);
                *(uint2*)&Vt[(bh * HS_ + d0 + lr) * S_ + s0] = *(const uint2*)o;
            } else {
                bf16_t* O = which ? Ko : Qo;
#pragma unroll
                for (int j = 0; j < 4; j++)
                    O[(bh * S_ + s0 + j) * HS_ + d0 + lr] = f2b(acc[mm][n][j]);
            }
        }
    }
}

// ---------------- causal flash attention (r8 structure, best known) ---------
__device__ __forceinline__ void attn_stage(bf16_t* Kd, bf16_t* Vd,
                                           const bf16_t* Kg, const bf16_t* Vg,
                                           int kv0, int wid, int lane) {
#pragma unroll
    for (int jj = 0; jj < 4; jj++) {
        const int c = (wid << 2) + jj;
        const int rk = (c << 2) + (lane >> 4);        // K row 0..63
        async16(Kd + c * 512,
                Kg + (size_t)(kv0 + rk) * HS_ + (((lane & 15) ^ (rk & 7)) << 3));
        const int rv = (c << 3) + (lane >> 3);        // V^T row 0..127
        async16(Vd + c * 512,
                Vg + (size_t)rv * S_ + kv0 + (((lane & 7) ^ (rv & 7)) << 3));
    }
}

__global__ __launch_bounds__(256) void attn_fwd(const bf16_t* __restrict__ Q,
                                                const bf16_t* __restrict__ Kv,
                                                const bf16_t* __restrict__ Vt,
                                                const float* __restrict__ amask,
                                                bf16_t* __restrict__ ctx) {
    __shared__ __align__(16) bf16_t Ks[2][64 * 128];
    __shared__ __align__(16) bf16_t Vs[2][128 * 64];
    __shared__ __align__(16) bf16_t Ps[4][16 * 72];

    const int id = (int)(blockIdx.x + (blockIdx.y << 4));     // 0..511
    const int wg = ((id & 7) << 6) + (id >> 3);               // XCD-bijective
    const int pair = wg & 15;
    const int bh = wg >> 4;
    const int b = bh >> 4, h = bh & 15;
    const int tid = threadIdx.x, wid = tid >> 6, lane = tid & 63;
    const int lr = lane & 15, ls = lane >> 4;
    const float* am = amask + (size_t)b * S_;
    const bf16_t* Kg = Kv + (size_t)bh * S_ * HS_;
    const bf16_t* Vg = Vt + (size_t)bh * HS_ * S_;

#pragma unroll 1
    for (int half = 0; half < 2; ++half) {
        const int qt = half ? pair : (31 - pair);
        const int q0 = qt << 6;
        const int qrow = q0 + wid * 16 + lr;     // this lane's q-row

        bf16x8 qf[4];
        const bf16_t* qp = Q + ((size_t)bh * S_ + qrow) * HS_;
#pragma unroll
        for (int dk = 0; dk < 4; dk++) qf[dk] = *(const bf16x8*)(qp + dk * 32 + ls * 8);

        float mrun = -3.0e38f, lrun = 0.f;
        f32x4 oacc[8];
#pragma unroll
        for (int dt = 0; dt < 8; dt++) oacc[dt] = (f32x4){0.f, 0.f, 0.f, 0.f};

        attn_stage(Ks[0], Vs[0], Kg, Vg, 0, wid, lane);

#pragma unroll 1
        for (int step = 0; step <= qt; ++step) {
            const int cur = step & 1;
            const int kv0 = step << 6;
            if (step < qt) {
                attn_stage(Ks[cur ^ 1], Vs[cur ^ 1], Kg, Vg, (step + 1) << 6, wid, lane);
                WAIT_VM8();
            } else {
                WAIT_VM0();
            }
            BAR();

            // swapped QK^T
            f32x4 sacc[4];
#pragma unroll
            for (int t = 0; t < 4; t++) sacc[t] = (f32x4){0.f, 0.f, 0.f, 0.f};
#pragma unroll
            for (int t = 0; t < 4; t++)
#pragma unroll
                for (int dk = 0; dk < 4; dk++) {
                    const int row = t * 16 + lr;
                    bf16x8 kf = *(const bf16x8*)
                        &Ks[cur][row * 128 + (((dk * 4 + ls) ^ (row & 7)) << 3)];
                    sacc[t] = mfma16(kf, qf[dk], sacc[t]);
                }

            const bool diag = (step == qt);
            float sv[4][4];
            float rmax = -3.0e38f;
#pragma unroll
            for (int t = 0; t < 4; t++) {
                const float4 amv = *(const float4*)&am[kv0 + t * 16 + ls * 4];
                const float amj[4] = { amv.x, amv.y, amv.z, amv.w };
#pragma unroll
                for (int j = 0; j < 4; j++) {
                    const int kvp = kv0 + t * 16 + ls * 4 + j;
                    float v = sacc[t][j] * NORM_ + amj[j];
                    if (diag && kvp > qrow) v = -3.0e38f;
                    sv[t][j] = v;
                    rmax = fmaxf(rmax, v);
                }
            }
            rmax = fmaxf(rmax, __shfl_xor(rmax, 16));
            rmax = fmaxf(rmax, __shfl_xor(rmax, 32));

            if (!__all((int)(rmax <= mrun))) {
                const float mnew = fmaxf(mrun, rmax);
                const float sc = __expf(mrun - mnew);
                lrun *= sc;
                mrun = mnew;
                float scb[4];
#pragma unroll
                for (int j = 0; j < 4; j++) scb[j] = __shfl(sc, ls * 4 + j);
#pragma unroll
                for (int dt = 0; dt < 8; dt++)
#pragma unroll
                    for (int j = 0; j < 4; j++) oacc[dt][j] *= scb[j];
            }

            float psum = 0.f;
#pragma unroll
            for (int t = 0; t < 4; t++) {
                const float p0 = __expf(sv[t][0] - mrun);
                const float p1 = __expf(sv[t][1] - mrun);
                const float p2 = __expf(sv[t][2] - mrun);
                const float p3 = __expf(sv[t][3] - mrun);
                psum += (p0 + p1) + (p2 + p3);
                const unsigned pk0 = (unsigned)f2b(p0) | ((unsigned)f2b(p1) << 16);
                const unsigned pk1 = (unsigned)f2b(p2) | ((unsigned)f2b(p3) << 16);
                *(unsigned*)&Ps[wid][lr * 72 + t * 16 + ls * 4]     = pk0;
                *(unsigned*)&Ps[wid][lr * 72 + t * 16 + ls * 4 + 2] = pk1;
            }
            psum += __shfl_xor(psum, 16);
            psum += __shfl_xor(psum, 32);
            lrun += psum;

            bf16x8 pf[2];
#pragma unroll
            for (int hh = 0; hh < 2; hh++)
                pf[hh] = *(const bf16x8*)&Ps[wid][lr * 72 + hh * 32 + ls * 8];
#pragma unroll
            for (int dt = 0; dt < 8; dt++)
#pragma unroll
                for (int hh = 0; hh < 2; hh++) {
                    const int vrow = dt * 16 + lr;
                    bf16x8 vf = *(const bf16x8*)
                        &Vs[cur][vrow * 64 + (((hh * 4 + ls) ^ (vrow & 7)) << 3)];
                    oacc[dt] = mfma16(pf[hh], vf, oacc[dt]);
                }
            BAR();
        }

        const float inv = 1.0f / lrun;           // q=lr layout
        float invj[4];
#pragma unroll
        for (int j = 0; j < 4; j++) invj[j] = __shfl(inv, ls * 4 + j);
#pragma unroll
        for (int j = 0; j < 4; j++) {
            bf16_t* dst = ctx + ((size_t)b * S_ + q0 + wid * 16 + ls * 4 + j) * H_ + h * HS_;
#pragma unroll
            for (int dt = 0; dt < 8; dt++) dst[dt * 16 + lr] = f2b(oacc[dt][j] * invj[j]);
        }
    }
}

extern "C" void kernel_launch(void* const* d_in, const int* in_sizes, int n_in,
                              void* d_out, int out_size, void* d_ws, size_t ws_size,
                              hipStream_t stream) {
    const float* hs   = (const float*)d_in[0];
    const float* am   = (const float*)d_in[1];
    const int*   pos  = (const int*)d_in[2];
    const float* Wqkv = (const float*)d_in[3];
    const float* bqkv = (const float*)d_in[4];
    const float* Wd   = (const float*)d_in[5];
    const float* bd   = (const float*)d_in[6];
    float* out = (float*)d_out;
    char*  ws  = (char*)d_ws;

    const size_t MB = 1024 * 1024;
    bf16_t* X    = (bf16_t*)(ws);              // 16 MB (reused as ctx)
    bf16_t* WqT  = (bf16_t*)(ws + 16 * MB);    // 24 MB
    bf16_t* WdT  = (bf16_t*)(ws + 40 * MB);    // 8 MB
    bf16_t* Qb   = (bf16_t*)(ws + 48 * MB);    // 16 MB
    bf16_t* Kb   = (bf16_t*)(ws + 64 * MB);    // 16 MB
    bf16_t* Vtb  = (bf16_t*)(ws + 80 * MB);    // 16 MB
    bf16_t* ctx  = X;

    cvt_bf16<<<4096, 256, 0, stream>>>(hs, X);
    transpose_cvt<<<dim3(6144 / 64, 2048 / 64), 256, 0, stream>>>(Wqkv, WqT, 2048, 6144);
    transpose_cvt<<<dim3(2048 / 64, 2048 / 64), 256, 0, stream>>>(Wd, WdT, 2048, 2048);
    gemm_qkv_fused<<<dim3(32, 32), 512, 0, stream>>>(X, WqT, bqkv, pos,
                                                     Qb, Kb, Vtb, 4096, 6144, 2048);
    attn_fwd<<<dim3(16, 32), 256, 0, stream>>>(Qb, Kb, Vtb, am, ctx);
    gemm_bias<0><<<dim3(16, 32), 256, 0, stream>>>(ctx, WdT, bd, out, 4096, 2048, 2048);
}

// Round 18
// 252.956 us; speedup vs baseline: 1.5252x; 1.0675x over previous
//
#include <hip/hip_runtime.h>

#define B_   2
#define S_   2048
#define H_   2048
#define NH_  16
#define HS_  128
#define NORM_ 0.08838834764831845f          // 128^-0.5
#define L2B16 0.8304820237218407f           // log2(10000)/16

typedef unsigned short bf16_t;
typedef __bf16 bf16x8 __attribute__((ext_vector_type(8)));
typedef float  f32x4  __attribute__((ext_vector_type(4)));

__device__ __forceinline__ float b2f(bf16_t u) {
    return __uint_as_float(((unsigned int)u) << 16);
}
__device__ __forceinline__ bf16_t f2b(float f) {
    unsigned int x = __float_as_uint(f);
    x += 0x7fffu + ((x >> 16) & 1u);        // round-to-nearest-even
    return (bf16_t)(x >> 16);
}

__device__ __forceinline__ void async16(bf16_t* lds, const bf16_t* g) {
    __builtin_amdgcn_global_load_lds(
        (const __attribute__((address_space(1))) void*)g,
        (__attribute__((address_space(3))) void*)lds, 16, 0, 0);
}

__device__ __forceinline__ f32x4 mfma16(bf16x8 a, bf16x8 b, f32x4 c) {
    return __builtin_amdgcn_mfma_f32_16x16x32_bf16(a, b, c, 0, 0, 0);
}

#define BAR()        asm volatile("s_barrier" ::: "memory")
#define WAIT_VM0()   asm volatile("s_waitcnt vmcnt(0)" ::: "memory")
#define WAIT_VM8()   asm volatile("s_waitcnt vmcnt(8)" ::: "memory")

// ---------------- f32 -> bf16 convert (8 elems/thread) ----------------
__global__ __launch_bounds__(256) void cvt_bf16(const float* __restrict__ in,
                                                bf16_t* __restrict__ out) {
    const size_t i = (size_t)blockIdx.x * 256 + threadIdx.x;
    const float4* p = (const float4*)in + i * 2;
    float4 a = p[0], b = p[1];
    bf16_t o[8] = { f2b(a.x), f2b(a.y), f2b(a.z), f2b(a.w),
                    f2b(b.x), f2b(b.y), f2b(b.z), f2b(b.w) };
    *((bf16x8*)out + i) = *(const bf16x8*)o;
}

// ---------------- W (KxN f32) -> W^T (NxK bf16), 64x64 tiles, vectorized ----
__global__ __launch_bounds__(256) void transpose_cvt(const float* __restrict__ W,
                                                     bf16_t* __restrict__ WT,
                                                     int K, int N) {
    __shared__ float t[64][65];
    const int n0 = blockIdx.x * 64, k0 = blockIdx.y * 64;
    const int tid = threadIdx.x;
    const int cx = tid & 15, r0 = tid >> 4;
#pragma unroll
    for (int p = 0; p < 4; p++) {
        const int row = p * 16 + r0;
        const float4 v = *(const float4*)&W[(size_t)(k0 + row) * N + n0 + cx * 4];
        t[row][cx * 4 + 0] = v.x;
        t[row][cx * 4 + 1] = v.y;
        t[row][cx * 4 + 2] = v.z;
        t[row][cx * 4 + 3] = v.w;
    }
    __syncthreads();
    const int n = tid >> 2, k8 = tid & 3;
#pragma unroll
    for (int p = 0; p < 2; p++) {
        const int kk = (k8 + p * 4) * 8;
        bf16_t o[8];
#pragma unroll
        for (int i = 0; i < 8; i++) o[i] = f2b(t[kk + i][n]);
        *(bf16x8*)&WT[(size_t)(n0 + n) * K + k0 + kk] = *(const bf16x8*)o;
    }
}

// ---------------- shared staging helper (512-thread blocks) ----------------
__device__ __forceinline__ void st512(bf16_t* lds, const bf16_t* g,
                                      int K, int part, int tid) {
    const int idx = part * 512 + tid;
    const int row = idx >> 3, slot = idx & 7;
    async16(lds + idx * 8, g + (size_t)row * K + ((slot ^ (row & 7)) << 3));
}

// A-frag load for BM=128 (per-wave 64 rows): q in {0,1}
#define LDAQ2(dst, ab, q) do {                                                 \
    _Pragma("unroll")                                                          \
    for (int m = 0; m < 2; m++)                                                \
        _Pragma("unroll")                                                      \
        for (int ks = 0; ks < 2; ks++) {                                       \
            const int r = wm * 64 + (q) * 32 + m * 16 + lr;                    \
            dst[m][ks] = *(const bf16x8*)                                      \
                &(ab)[r * 64 + (((ks * 4 + ls) ^ (r & 7)) << 3)];              \
        }                                                                      \
} while (0)

#define LDB3(bb) do {                                                          \
    _Pragma("unroll")                                                          \
    for (int n = 0; n < 3; n++)                                                \
        _Pragma("unroll")                                                      \
        for (int ks = 0; ks < 2; ks++) {                                       \
            const int r = wn * 48 + n * 16 + lr;                               \
            bfr[n][ks] = *(const bf16x8*)                                      \
                &(bb)[r * 64 + (((ks * 4 + ls) ^ (r & 7)) << 3)];              \
        }                                                                      \
} while (0)

#define MMA3(q, src) do {                                                      \
    __builtin_amdgcn_s_setprio(1);                                             \
    _Pragma("unroll")                                                          \
    for (int ks = 0; ks < 2; ks++)                                             \
        _Pragma("unroll")                                                      \
        for (int n = 0; n < 3; n++)                                            \
            _Pragma("unroll")                                                  \
            for (int m = 0; m < 2; m++)                                        \
                acc[(q) * 2 + m][n] =                                          \
                    mfma16(src[m][ks], bfr[n][ks], acc[(q) * 2 + m][n]);       \
    __builtin_amdgcn_s_setprio(0);                                             \
} while (0)

#define LDB2D(bb) do {                                                         \
    _Pragma("unroll")                                                          \
    for (int n = 0; n < 2; n++)                                                \
        _Pragma("unroll")                                                      \
        for (int ks = 0; ks < 2; ks++) {                                       \
            const int r = wn * 32 + n * 16 + lr;                               \
            bfr[n][ks] = *(const bf16x8*)                                      \
                &(bb)[r * 64 + (((ks * 4 + ls) ^ (r & 7)) << 3)];              \
        }                                                                      \
} while (0)

#define MMA2D(q, src) do {                                                     \
    __builtin_amdgcn_s_setprio(1);                                             \
    _Pragma("unroll")                                                          \
    for (int ks = 0; ks < 2; ks++)                                             \
        _Pragma("unroll")                                                      \
        for (int n = 0; n < 2; n++)                                            \
            _Pragma("unroll")                                                  \
            for (int m = 0; m < 2; m++)                                        \
                acc[(q) * 2 + m][n] =                                          \
                    mfma16(src[m][ks], bfr[n][ks], acc[(q) * 2 + m][n]);       \
    __builtin_amdgcn_s_setprio(0);                                             \
} while (0)

// ---------------- dense GEMM: 128x128, BK=64 dbuf, 64KB LDS (2 blocks/CU) ---
// grid (16,32) = 512 blocks: ALL co-resident in one round (2/CU).
__global__ __launch_bounds__(512, 2) void gemm_dense(const bf16_t* __restrict__ A,
                                                     const bf16_t* __restrict__ BT,
                                                     const float* __restrict__ bias,
                                                     float* __restrict__ C,
                                                     int M, int N, int K) {
    __shared__ __align__(16) bf16_t As[2][128 * 64];
    __shared__ __align__(16) bf16_t Bs[2][128 * 64];

    const int id  = (int)(blockIdx.y * gridDim.x + blockIdx.x);   // 0..511
    const int xcd = id & 7, j0 = id >> 3;                         // j0 0..63
    const int bx  = (xcd & 1) * 8 + (j0 & 7);      // 0..15
    const int by  = (xcd >> 1) * 8 + (j0 >> 3);    // 0..31

    const int tid = threadIdx.x;
    const int wid = tid >> 6, lane = tid & 63;
    const int lr = lane & 15, ls = lane >> 4;
    const int wm = wid >> 2, wn = wid & 3;
    const size_t m0 = (size_t)by * 128, n0 = (size_t)bx * 128;

    const bf16_t* Ab = A + m0 * K;
    const bf16_t* Bb = BT + n0 * K;

    f32x4 acc[4][2];
#pragma unroll
    for (int m = 0; m < 4; m++)
#pragma unroll
        for (int n = 0; n < 2; n++) acc[m][n] = (f32x4){0.f, 0.f, 0.f, 0.f};
    bf16x8 bfr[2][2];
    bf16x8 afP[2][2], afQ[2][2];

#pragma unroll
    for (int p = 0; p < 2; p++) st512(As[0], Ab, K, p, tid);
#pragma unroll
    for (int p = 0; p < 2; p++) st512(Bs[0], Bb, K, p, tid);
    WAIT_VM0();
    BAR();

    const int nt = K >> 6;
#pragma unroll 1
    for (int i = 0; i < nt; ++i) {
        const int c = i & 1;
        const bf16_t* Ac = As[c];
        const bf16_t* Bc = Bs[c];
        if (i + 1 < nt) {
            const size_t ko = (size_t)(i + 1) * 64;
            bf16_t* Ad = As[c ^ 1];
            bf16_t* Bd = Bs[c ^ 1];
#pragma unroll
            for (int p = 0; p < 2; p++) st512(Ad, Ab + ko, K, p, tid);
#pragma unroll
            for (int p = 0; p < 2; p++) st512(Bd, Bb + ko, K, p, tid);
        }
        __builtin_amdgcn_sched_barrier(0);
        LDAQ2(afP, Ac, 0);
        LDB2D(Bc);
        LDAQ2(afQ, Ac, 1);
        MMA2D(0, afP);
        MMA2D(1, afQ);
        WAIT_VM0();
        BAR();
    }

    float bv[2];
#pragma unroll
    for (int n = 0; n < 2; n++) bv[n] = bias[n0 + wn * 32 + n * 16 + lr];
#pragma unroll
    for (int mm = 0; mm < 4; mm++)
#pragma unroll
        for (int n = 0; n < 2; n++)
#pragma unroll
            for (int j = 0; j < 4; j++) {
                const size_t row = m0 + wm * 64 + mm * 16 + ls * 4 + j;
                const size_t col = n0 + wn * 32 + n * 16 + lr;
                C[row * N + col] = acc[mm][n][j] + bv[n];
            }
}

// ---------------- fused QKV GEMM: 128x192, 80KB LDS (2 blocks/CU) -----------
__global__ __launch_bounds__(512, 2) void gemm_qkv_fused(
        const bf16_t* __restrict__ A, const bf16_t* __restrict__ BT,
        const float* __restrict__ bias, const int* __restrict__ pos_ids,
        bf16_t* __restrict__ Qo, bf16_t* __restrict__ Ko,
        bf16_t* __restrict__ Vt, int M, int N, int K) {
    __shared__ __align__(16) bf16_t As[2][128 * 64];
    __shared__ __align__(16) bf16_t Bs[2][192 * 64];

    const int id  = (int)(blockIdx.y * gridDim.x + blockIdx.x);   // 0..1023
    const int xcd = id & 7, j0 = id >> 3;                         // j0 0..127
    const int bx  = (xcd & 3) * 8 + (j0 & 7);      // 0..31
    const int by  = (xcd >> 2) * 16 + (j0 >> 3);   // 0..31

    const int tid = threadIdx.x;
    const int wid = tid >> 6, lane = tid & 63;
    const int lr = lane & 15, ls = lane >> 4;
    const int wm = wid >> 2, wn = wid & 3;
    const size_t m0 = (size_t)by * 128, n0 = (size_t)bx * 192;

    const bf16_t* Ab = A + m0 * K;
    const bf16_t* Bb = BT + n0 * K;

    f32x4 acc[4][3];
#pragma unroll
    for (int m = 0; m < 4; m++)
#pragma unroll
        for (int n = 0; n < 3; n++) acc[m][n] = (f32x4){0.f, 0.f, 0.f, 0.f};
    bf16x8 bfr[3][2];
    bf16x8 afP[2][2], afQ[2][2];

#pragma unroll
    for (int p = 0; p < 2; p++) st512(As[0], Ab, K, p, tid);
#pragma unroll
    for (int p = 0; p < 3; p++) st512(Bs[0], Bb, K, p, tid);
    WAIT_VM0();
    BAR();

    const int nt = K >> 6;
#pragma unroll 1
    for (int i = 0; i < nt; ++i) {
        const int c = i & 1;
        const bf16_t* Ac = As[c];
        const bf16_t* Bc = Bs[c];
        if (i + 1 < nt) {
            const size_t ko = (size_t)(i + 1) * 64;
            bf16_t* Ad = As[c ^ 1];
            bf16_t* Bd = Bs[c ^ 1];
#pragma unroll
            for (int p = 0; p < 2; p++) st512(Ad, Ab + ko, K, p, tid);
#pragma unroll
            for (int p = 0; p < 3; p++) st512(Bd, Bb + ko, K, p, tid);
        }
        __builtin_amdgcn_sched_barrier(0);
        LDAQ2(afP, Ac, 0);
        LDB3(Bc);
        LDAQ2(afQ, Ac, 1);
        MMA3(0, afP);
        MMA3(1, afQ);
        WAIT_VM0();
        BAR();
    }

    // -------- epilogue: bias, RoPE (one cross-wave exchange), scatter --------
    const bool evenbx = ((bx & 1) == 0);
    const int  nh     = bx >> 1;
    {
        float bv[3];
#pragma unroll
        for (int n = 0; n < 3; n++) bv[n] = bias[n0 + wn * 48 + n * 16 + lr];
#pragma unroll
        for (int mm = 0; mm < 4; mm++)
#pragma unroll
            for (int n = 0; n < 3; n++)
#pragma unroll
                for (int j = 0; j < 4; j++) acc[mm][n][j] += bv[n];
    }

    // exchange K(d0=0) <-> K(d0=16) for even tiles (wn2.n2 <-> wn3.n0)
    float* XB = (float*)&As[0][0];               // dead after final BAR
    if (evenbx && wn == 2) {
#pragma unroll
        for (int mm = 0; mm < 4; mm++)
#pragma unroll
            for (int j = 0; j < 4; j++)
                XB[((((wm * 4 + mm) * 4 + ls) * 4 + j) * 16) + lr] = acc[mm][2][j];
    }
    if (evenbx && wn == 3) {
#pragma unroll
        for (int mm = 0; mm < 4; mm++)
#pragma unroll
            for (int j = 0; j < 4; j++)
                XB[2048 + ((((wm * 4 + mm) * 4 + ls) * 4 + j) * 16) + lr] = acc[mm][0][j];
    }
    __syncthreads();

    const float invf = __builtin_exp2f(-(float)lr * L2B16);

    if (evenbx && wn == 0) {                     // Q rot: n=0 (d=lr), n=1 (d=16+lr)
#pragma unroll
        for (int mm = 0; mm < 4; mm++) {
            const int row0 = (int)m0 + wm * 64 + mm * 16 + ls * 4;
#pragma unroll
            for (int j = 0; j < 4; j++) {
                const float th = (float)pos_ids[row0 + j] * invf;
                const float c = __cosf(th), sn = __sinf(th);
                const float x = acc[mm][0][j], y = acc[mm][1][j];
                acc[mm][0][j] = x * c - y * sn;
                acc[mm][1][j] = y * c + x * sn;
            }
        }
    }
    if (evenbx && wn == 2) {                     // K low rot: n=2 (d=lr)
#pragma unroll
        for (int mm = 0; mm < 4; mm++) {
            const int row0 = (int)m0 + wm * 64 + mm * 16 + ls * 4;
#pragma unroll
            for (int j = 0; j < 4; j++) {
                const float th = (float)pos_ids[row0 + j] * invf;
                const float c = __cosf(th), sn = __sinf(th);
                const float y = XB[2048 + ((((wm * 4 + mm) * 4 + ls) * 4 + j) * 16) + lr];
                acc[mm][2][j] = acc[mm][2][j] * c - y * sn;
            }
        }
    }
    if (evenbx && wn == 3) {                     // K high rot: n=0 (d=16+lr)
#pragma unroll
        for (int mm = 0; mm < 4; mm++) {
            const int row0 = (int)m0 + wm * 64 + mm * 16 + ls * 4;
#pragma unroll
            for (int j = 0; j < 4; j++) {
                const float th = (float)pos_ids[row0 + j] * invf;
                const float c = __cosf(th), sn = __sinf(th);
                const float y = XB[((((wm * 4 + mm) * 4 + ls) * 4 + j) * 16) + lr];
                acc[mm][0][j] = acc[mm][0][j] * c + y * sn;
            }
        }
    }

    // stores
#pragma unroll
    for (int n = 0; n < 3; n++) {
        const int off = wn * 48 + n * 16;
        int which, d0;
        if (evenbx) { which = (off < 128) ? 0 : 1; d0 = (off < 128) ? off : off - 128; }
        else        { which = (off < 64) ? 1 : 2;  d0 = (off < 64) ? off + 64 : off - 64; }
#pragma unroll
        for (int mm = 0; mm < 4; mm++) {
            const int row0 = (int)m0 + wm * 64 + mm * 16 + ls * 4;
            const int b = row0 >> 11, s0 = row0 & 2047;
            const size_t bh = (size_t)(b * NH_ + nh);
            if (which == 2) {                    // V -> V^T[bh][d][s]
                bf16_t o[4];
#pragma unroll
                for (int j = 0; j < 4; j++) o[j] = f2b(acc[mm][n][j]);
                *(uint2*)&Vt[(bh * HS_ + d0 + lr) * S_ + s0] = *(const uint2*)o;
            } else {
                bf16_t* O = which ? Ko : Qo;
#pragma unroll
                for (int j = 0; j < 4; j++)
                    O[(bh * S_ + s0 + j) * HS_ + d0 + lr] = f2b(acc[mm][n][j]);
            }
        }
    }
}

// ---------------- causal flash attention (r8 structure, best known) ---------
__device__ __forceinline__ void attn_stage(bf16_t* Kd, bf16_t* Vd,
                                           const bf16_t* Kg, const bf16_t* Vg,
                                           int kv0, int wid, int lane) {
#pragma unroll
    for (int jj = 0; jj < 4; jj++) {
        const int c = (wid << 2) + jj;
        const int rk = (c << 2) + (lane >> 4);        // K row 0..63
        async16(Kd + c * 512,
                Kg + (size_t)(kv0 + rk) * HS_ + (((lane & 15) ^ (rk & 7)) << 3));
        const int rv = (c << 3) + (lane >> 3);        // V^T row 0..127
        async16(Vd + c * 512,
                Vg + (size_t)rv * S_ + kv0 + (((lane & 7) ^ (rv & 7)) << 3));
    }
}

__global__ __launch_bounds__(256) void attn_fwd(const bf16_t* __restrict__ Q,
                                                const bf16_t* __restrict__ Kv,
                                                const bf16_t* __restrict__ Vt,
                                                const float* __restrict__ amask,
                                                bf16_t* __restrict__ ctx) {
    __shared__ __align__(16) bf16_t Ks[2][64 * 128];
    __shared__ __align__(16) bf16_t Vs[2][128 * 64];
    __shared__ __align__(16) bf16_t Ps[4][16 * 72];

    const int id = (int)(blockIdx.x + (blockIdx.y << 4));     // 0..511
    const int wg = ((id & 7) << 6) + (id >> 3);               // XCD-bijective
    const int pair = wg & 15;
    const int bh = wg >> 4;
    const int b = bh >> 4, h = bh & 15;
    const int tid = threadIdx.x, wid = tid >> 6, lane = tid & 63;
    const int lr = lane & 15, ls = lane >> 4;
    const float* am = amask + (size_t)b * S_;
    const bf16_t* Kg = Kv + (size_t)bh * S_ * HS_;
    const bf16_t* Vg = Vt + (size_t)bh * HS_ * S_;

#pragma unroll 1
    for (int half = 0; half < 2; ++half) {
        const int qt = half ? pair : (31 - pair);
        const int q0 = qt << 6;
        const int qrow = q0 + wid * 16 + lr;     // this lane's q-row

        bf16x8 qf[4];
        const bf16_t* qp = Q + ((size_t)bh * S_ + qrow) * HS_;
#pragma unroll
        for (int dk = 0; dk < 4; dk++) qf[dk] = *(const bf16x8*)(qp + dk * 32 + ls * 8);

        float mrun = -3.0e38f, lrun = 0.f;
        f32x4 oacc[8];
#pragma unroll
        for (int dt = 0; dt < 8; dt++) oacc[dt] = (f32x4){0.f, 0.f, 0.f, 0.f};

        attn_stage(Ks[0], Vs[0], Kg, Vg, 0, wid, lane);

#pragma unroll 1
        for (int step = 0; step <= qt; ++step) {
            const int cur = step & 1;
            const int kv0 = step << 6;
            if (step < qt) {
                attn_stage(Ks[cur ^ 1], Vs[cur ^ 1], Kg, Vg, (step + 1) << 6, wid, lane);
                WAIT_VM8();
            } else {
                WAIT_VM0();
            }
            BAR();

            // swapped QK^T
            f32x4 sacc[4];
#pragma unroll
            for (int t = 0; t < 4; t++) sacc[t] = (f32x4){0.f, 0.f, 0.f, 0.f};
#pragma unroll
            for (int t = 0; t < 4; t++)
#pragma unroll
                for (int dk = 0; dk < 4; dk++) {
                    const int row = t * 16 + lr;
                    bf16x8 kf = *(const bf16x8*)
                        &Ks[cur][row * 128 + (((dk * 4 + ls) ^ (row & 7)) << 3)];
                    sacc[t] = mfma16(kf, qf[dk], sacc[t]);
                }

            const bool diag = (step == qt);
            float sv[4][4];
            float rmax = -3.0e38f;
#pragma unroll
            for (int t = 0; t < 4; t++) {
                const float4 amv = *(const float4*)&am[kv0 + t * 16 + ls * 4];
                const float amj[4] = { amv.x, amv.y, amv.z, amv.w };
#pragma unroll
                for (int j = 0; j < 4; j++) {
                    const int kvp = kv0 + t * 16 + ls * 4 + j;
                    float v = sacc[t][j] * NORM_ + amj[j];
                    if (diag && kvp > qrow) v = -3.0e38f;
                    sv[t][j] = v;
                    rmax = fmaxf(rmax, v);
                }
            }
            rmax = fmaxf(rmax, __shfl_xor(rmax, 16));
            rmax = fmaxf(rmax, __shfl_xor(rmax, 32));

            if (!__all((int)(rmax <= mrun))) {
                const float mnew = fmaxf(mrun, rmax);
                const float sc = __expf(mrun - mnew);
                lrun *= sc;
                mrun = mnew;
                float scb[4];
#pragma unroll
                for (int j = 0; j < 4; j++) scb[j] = __shfl(sc, ls * 4 + j);
#pragma unroll
                for (int dt = 0; dt < 8; dt++)
#pragma unroll
                    for (int j = 0; j < 4; j++) oacc[dt][j] *= scb[j];
            }

            float psum = 0.f;
#pragma unroll
            for (int t = 0; t < 4; t++) {
                const float p0 = __expf(sv[t][0] - mrun);
                const float p1 = __expf(sv[t][1] - mrun);
                const float p2 = __expf(sv[t][2] - mrun);
                const float p3 = __expf(sv[t][3] - mrun);
                psum += (p0 + p1) + (p2 + p3);
                const unsigned pk0 = (unsigned)f2b(p0) | ((unsigned)f2b(p1) << 16);
                const unsigned pk1 = (unsigned)f2b(p2) | ((unsigned)f2b(p3) << 16);
                *(unsigned*)&Ps[wid][lr * 72 + t * 16 + ls * 4]     = pk0;
                *(unsigned*)&Ps[wid][lr * 72 + t * 16 + ls * 4 + 2] = pk1;
            }
            psum += __shfl_xor(psum, 16);
            psum += __shfl_xor(psum, 32);
            lrun += psum;

            bf16x8 pf[2];
#pragma unroll
            for (int hh = 0; hh < 2; hh++)
                pf[hh] = *(const bf16x8*)&Ps[wid][lr * 72 + hh * 32 + ls * 8];
#pragma unroll
            for (int dt = 0; dt < 8; dt++)
#pragma unroll
                for (int hh = 0; hh < 2; hh++) {
                    const int vrow = dt * 16 + lr;
                    bf16x8 vf = *(const bf16x8*)
                        &Vs[cur][vrow * 64 + (((hh * 4 + ls) ^ (vrow & 7)) << 3)];
                    oacc[dt] = mfma16(pf[hh], vf, oacc[dt]);
                }
            BAR();
        }

        const float inv = 1.0f / lrun;           // q=lr layout
        float invj[4];
#pragma unroll
        for (int j = 0; j < 4; j++) invj[j] = __shfl(inv, ls * 4 + j);
#pragma unroll
        for (int j = 0; j < 4; j++) {
            bf16_t* dst = ctx + ((size_t)b * S_ + q0 + wid * 16 + ls * 4 + j) * H_ + h * HS_;
#pragma unroll
            for (int dt = 0; dt < 8; dt++) dst[dt * 16 + lr] = f2b(oacc[dt][j] * invj[j]);
        }
    }
}

extern "C" void kernel_launch(void* const* d_in, const int* in_sizes, int n_in,
                              void* d_out, int out_size, void* d_ws, size_t ws_size,
                              hipStream_t stream) {
    const float* hs   = (const float*)d_in[0];
    const float* am   = (const float*)d_in[1];
    const int*   pos  = (const int*)d_in[2];
    const float* Wqkv = (const float*)d_in[3];
    const float* bqkv = (const float*)d_in[4];
    const float* Wd   = (const float*)d_in[5];
    const float* bd   = (const float*)d_in[6];
    float* out = (float*)d_out;
    char*  ws  = (char*)d_ws;

    const size_t MB = 1024 * 1024;
    bf16_t* X    = (bf16_t*)(ws);              // 16 MB (reused as ctx)
    bf16_t* WqT  = (bf16_t*)(ws + 16 * MB);    // 24 MB
    bf16_t* WdT  = (bf16_t*)(ws + 40 * MB);    // 8 MB
    bf16_t* Qb   = (bf16_t*)(ws + 48 * MB);    // 16 MB
    bf16_t* Kb   = (bf16_t*)(ws + 64 * MB);    // 16 MB
    bf16_t* Vtb  = (bf16_t*)(ws + 80 * MB);    // 16 MB
    bf16_t* ctx  = X;

    cvt_bf16<<<4096, 256, 0, stream>>>(hs, X);
    transpose_cvt<<<dim3(6144 / 64, 2048 / 64), 256, 0, stream>>>(Wqkv, WqT, 2048, 6144);
    transpose_cvt<<<dim3(2048 / 64, 2048 / 64), 256, 0, stream>>>(Wd, WdT, 2048, 2048);
    gemm_qkv_fused<<<dim3(32, 32), 512, 0, stream>>>(X, WqT, bqkv, pos,
                                                     Qb, Kb, Vtb, 4096, 6144, 2048);
    attn_fwd<<<dim3(16, 32), 256, 0, stream>>>(Qb, Kb, Vtb, am, ctx);
    gemm_dense<<<dim3(16, 32), 512, 0, stream>>>(ctx, WdT, bd, out, 4096, 2048, 2048);
}